// Round 5
// baseline (4668.307 us; speedup 1.0000x reference)
//
#include <hip/hip_runtime.h>
#include <hip/hip_bf16.h>
#include <math.h>

// ---------------- static config ----------------
// B=4, H=W=256, TIN=10, F=4, P=8, CIN=12, E=768, NB=8, BS=96,
// HP=WP=32, MID=3072, DEPTH=4, LAM=0.01, WF=17, TOK=4096, POS=B*32*17=2176

typedef __attribute__((ext_vector_type(8))) _Float16 half8;
typedef __attribute__((ext_vector_type(4))) _Float16 half4v;
typedef __attribute__((ext_vector_type(4))) float float4v;

__device__ __forceinline__ float gelu_f(float v) {
    return 0.5f * v * (1.0f + erff(v * 0.70710678118654752f));
}
__device__ __forceinline__ float shrink_f(float v) {
    return (v > 0.01f) ? (v - 0.01f) : ((v < -0.01f) ? (v + 0.01f) : 0.0f);
}

#define STEP32 0.19634954084936207f  // 2*pi/32

// async 16B global->LDS (lds dest wave-uniform; HW adds lane*16)
__device__ __forceinline__ void async16(const void* g, void* l) {
    __builtin_amdgcn_global_load_lds(
        (const __attribute__((address_space(1))) unsigned int*)g,
        (__attribute__((address_space(3))) unsigned int*)l, 16, 0, 0);
}

__device__ __forceinline__ half8 ld_f32x8_as_h8(const float* p) {
    float4 u = *(const float4*)p;
    float4 v = *(const float4*)(p + 4);
    half8 h;
    h[0] = (_Float16)u.x; h[1] = (_Float16)u.y; h[2] = (_Float16)u.z; h[3] = (_Float16)u.w;
    h[4] = (_Float16)v.x; h[5] = (_Float16)v.y; h[6] = (_Float16)v.z; h[7] = (_Float16)v.w;
    return h;
}

// ---------------- gather patches into A_h [4096][768] f16 ----------------
__global__ __launch_bounds__(256) void gather_patch(const float* __restrict__ x,
        const float* __restrict__ grd, _Float16* __restrict__ A)
{
    int idx = blockIdx.x * 256 + threadIdx.x;     // 0 .. 3,145,727
    int j   = idx % 768;
    int tok = idx / 768;
    int c = j >> 6, p = (j >> 3) & 7, q = j & 7;
    int wp = tok & 31, hp = (tok >> 5) & 31, b = tok >> 10;
    int hh = hp * 8 + p, ww = wp * 8 + q;
    float v;
    if (c < 10) v = x[((b * 256 + hh) * 256 + ww) * 10 + c];
    else        v = grd[((b * 256 + hh) * 256 + ww) * 2 + (c - 10)];
    A[idx] = (_Float16)v;
}

// ---------------- forward DFT along W (real -> 17 complex), scale 1/32 ----------------
// register-resident: thread = one (bh, c) column; twiddles via broadcast LUT
__global__ __launch_bounds__(256) void dft_fwd_w(const float* __restrict__ t,
        float* __restrict__ XWr, float* __restrict__ XWi)
{
    __shared__ float2 lut[32];
    int bh = blockIdx.x;            // b*32 + h
    int tid = threadIdx.x;
    if (tid < 32) { float a = tid * STEP32; lut[tid] = make_float2(cosf(a), sinf(a)); }
    __syncthreads();
    int c = blockIdx.y * 256 + tid;
    float v[32];
    #pragma unroll
    for (int w = 0; w < 32; ++w) v[w] = t[(bh * 32 + w) * 768 + c];
    for (int kw = 0; kw <= 16; ++kw) {
        float ar = 0.f, ai = 0.f;
        #pragma unroll
        for (int w = 0; w < 32; ++w) {
            float2 cs = lut[(kw * w) & 31];
            ar += v[w] * cs.x;
            ai -= v[w] * cs.y;
        }
        XWr[(bh * 17 + kw) * 768 + c] = ar * 0.03125f;
        XWi[(bh * 17 + kw) * 768 + c] = ai * 0.03125f;
    }
}

// ---------------- complex DFT along H (register-resident) ----------------
template<int INV>
__global__ __launch_bounds__(256) void dft_h(const float* __restrict__ inR, const float* __restrict__ inI,
        float* __restrict__ outR, float* __restrict__ outI)
{
    __shared__ float2 lut[32];
    int bk = blockIdx.x;            // b*17 + kw
    int b = bk / 17, kw = bk % 17;
    int tid = threadIdx.x;
    if (tid < 32) { float a = tid * STEP32; lut[tid] = make_float2(cosf(a), sinf(a)); }
    __syncthreads();
    int c = blockIdx.y * 256 + tid;
    float cr[32], ci[32];
    #pragma unroll
    for (int h = 0; h < 32; ++h) {
        cr[h] = inR[((b * 32 + h) * 17 + kw) * 768 + c];
        ci[h] = inI[((b * 32 + h) * 17 + kw) * 768 + c];
    }
    for (int kh = 0; kh < 32; ++kh) {
        float ar = 0.f, ai = 0.f;
        #pragma unroll
        for (int h = 0; h < 32; ++h) {
            float2 cs = lut[(kh * h) & 31];
            if (INV) { ar += cr[h] * cs.x - ci[h] * cs.y; ai += ci[h] * cs.x + cr[h] * cs.y; }
            else     { ar += cr[h] * cs.x + ci[h] * cs.y; ai += ci[h] * cs.x - cr[h] * cs.y; }
        }
        outR[((b * 32 + kh) * 17 + kw) * 768 + c] = ar;
        outI[((b * 32 + kh) * 17 + kw) * 768 + c] = ai;
    }
}

// ---------------- inverse DFT along W + residual; dual fp32/f16 write (register-resident) ----------------
__global__ __launch_bounds__(256) void dft_inv_w(const float* __restrict__ YWr, const float* __restrict__ YWi,
        float* __restrict__ t, _Float16* __restrict__ t_h)
{
    __shared__ float2 lut[32];
    int bh = blockIdx.x;
    int tid = threadIdx.x;
    if (tid < 32) { float a = tid * STEP32; lut[tid] = make_float2(cosf(a), sinf(a)); }
    __syncthreads();
    int c = blockIdx.y * 256 + tid;
    float yr[17], yi[16];
    #pragma unroll
    for (int k = 0; k <= 16; ++k) yr[k] = YWr[(bh * 17 + k) * 768 + c];
    #pragma unroll
    for (int k = 1; k <= 15; ++k) yi[k] = YWi[(bh * 17 + k) * 768 + c];
    for (int w = 0; w < 32; ++w) {
        float val = yr[0] + ((w & 1) ? -yr[16] : yr[16]);
        #pragma unroll
        for (int k = 1; k <= 15; ++k) {
            float2 cs = lut[(k * w) & 31];
            val += 2.f * (yr[k] * cs.x - yi[k] * cs.y);
        }
        int gi = (bh * 32 + w) * 768 + c;
        float r = val * 0.03125f + t[gi];
        t[gi] = r;
        t_h[gi] = (_Float16)r;
    }
}

// ---------------- spectral weight prep: [i][o] fp32 -> [o][i] f16, 128 matrices ----------------
__global__ __launch_bounds__(256) void prep_specw(const float* __restrict__ w1,
        const float* __restrict__ w2, _Float16* __restrict__ out)
{
    __shared__ float tile[96][97];
    int mid = blockIdx.x;
    int n  = mid & 7;
    int ri = (mid >> 3) & 1;
    int l  = (mid >> 4) & 1;
    int d  = mid >> 5;
    const float* src = (l ? w2 : w1) + ((size_t)(d * 2 + ri) * 8 + n) * 9216;
    for (int idx = threadIdx.x; idx < 9216; idx += 256)
        tile[idx / 96][idx % 96] = src[idx];
    __syncthreads();
    _Float16* dst = out + (size_t)mid * 9216;
    for (int idx = threadIdx.x; idx < 9216; idx += 256)
        dst[idx] = (_Float16)tile[idx % 96][idx / 96];   // dst[o][i] = src[i][o]
}

// ---------------- spectral block-diag complex MFMA layer ----------------
template<int IN_F16, int ACT>
__global__ __launch_bounds__(256) void spec_mfma(
        const void* __restrict__ inR_, const void* __restrict__ inI_,
        const _Float16* __restrict__ WtR, const _Float16* __restrict__ WtI,
        const float* __restrict__ bR, const float* __restrict__ bI,
        void* __restrict__ outR_, void* __restrict__ outI_)
{
    const int n   = blockIdx.y;
    const int m0  = blockIdx.x * 64;
    const int tid = threadIdx.x;
    const int wave = tid >> 6, lane = tid & 63;
    const int wr = wave >> 1, wc = wave & 1;
    const int lr = lane & 15, quad = lane >> 4;

    float4v accR[2][3], accI[2][3];
    #pragma unroll
    for (int i = 0; i < 2; ++i)
        #pragma unroll
        for (int j = 0; j < 3; ++j) {
            float4v z = {0.f, 0.f, 0.f, 0.f};
            accR[i][j] = z; accI[i][j] = z;
        }

    const _Float16* wRb = WtR + (size_t)n * 9216;
    const _Float16* wIb = WtI + (size_t)n * 9216;

    #pragma unroll
    for (int kc = 0; kc < 3; ++kc) {
        half8 aR[2], aI[2], aIn[2];
        #pragma unroll
        for (int i = 0; i < 2; ++i) {
            size_t off = (size_t)(m0 + wr * 32 + i * 16 + lr) * 768 + n * 96 + kc * 32 + quad * 8;
            if (IN_F16) {
                aR[i] = *(const half8*)((const _Float16*)inR_ + off);
                aI[i] = *(const half8*)((const _Float16*)inI_ + off);
            } else {
                aR[i] = ld_f32x8_as_h8((const float*)inR_ + off);
                aI[i] = ld_f32x8_as_h8((const float*)inI_ + off);
            }
            aIn[i] = -aI[i];
        }
        half8 bRf[3], bIf[3];
        #pragma unroll
        for (int j = 0; j < 3; ++j) {
            int o = wc * 48 + j * 16 + lr;
            bRf[j] = *(const half8*)&wRb[o * 96 + kc * 32 + quad * 8];
            bIf[j] = *(const half8*)&wIb[o * 96 + kc * 32 + quad * 8];
        }
        #pragma unroll
        for (int i = 0; i < 2; ++i)
            #pragma unroll
            for (int j = 0; j < 3; ++j) {
                accR[i][j] = __builtin_amdgcn_mfma_f32_16x16x32_f16(aR[i],  bRf[j], accR[i][j], 0, 0, 0);
                accR[i][j] = __builtin_amdgcn_mfma_f32_16x16x32_f16(aIn[i], bIf[j], accR[i][j], 0, 0, 0);
                accI[i][j] = __builtin_amdgcn_mfma_f32_16x16x32_f16(aI[i],  bRf[j], accI[i][j], 0, 0, 0);
                accI[i][j] = __builtin_amdgcn_mfma_f32_16x16x32_f16(aR[i],  bIf[j], accI[i][j], 0, 0, 0);
            }
    }

    #pragma unroll
    for (int j = 0; j < 3; ++j) {
        int ol = wc * 48 + j * 16 + lr;
        float br = bR[n * 96 + ol], bi = bI[n * 96 + ol];
        #pragma unroll
        for (int i = 0; i < 2; ++i) {
            int rowb = m0 + wr * 32 + i * 16 + quad * 4;
            #pragma unroll
            for (int r = 0; r < 4; ++r) {
                float vr = accR[i][j][r] + br;
                float vi = accI[i][j][r] + bi;
                size_t gi = (size_t)(rowb + r) * 768 + n * 96 + ol;
                if (ACT == 0) {
                    ((_Float16*)outR_)[gi] = (_Float16)gelu_f(vr);
                    ((_Float16*)outI_)[gi] = (_Float16)gelu_f(vi);
                } else {
                    ((float*)outR_)[gi] = shrink_f(vr);
                    ((float*)outI_)[gi] = shrink_f(vi);
                }
            }
        }
    }
}

// ---------------- f32 -> f16 elementwise (vectorized x4) ----------------
__global__ __launch_bounds__(256) void cvt_f16(const float* __restrict__ in,
        _Float16* __restrict__ out)
{
    int i = blockIdx.x * 256 + threadIdx.x;
    float4 v = ((const float4*)in)[i];
    half4v o;
    o.x = (_Float16)v.x; o.y = (_Float16)v.y; o.z = (_Float16)v.z; o.w = (_Float16)v.w;
    ((half4v*)out)[i] = o;
}

// ---------------- f32 [K][N] -> f16 [N][K] transpose ----------------
__global__ __launch_bounds__(256) void cvt_transpose(const float* __restrict__ in,
        _Float16* __restrict__ out, int K, int N)
{
    __shared__ float tile[32][33];
    int kb = blockIdx.x * 32, nb = blockIdx.y * 32;
    int tx = threadIdx.x & 31, ty = threadIdx.x >> 5;   // ty 0..7
    #pragma unroll
    for (int r = 0; r < 32; r += 8)
        tile[ty + r][tx] = in[(size_t)(kb + ty + r) * N + nb + tx];
    __syncthreads();
    #pragma unroll
    for (int r = 0; r < 32; r += 8)
        out[(size_t)(nb + ty + r) * K + kb + tx] = (_Float16)tile[tx][ty + r];
}

// ---------------- fp16 MFMA GEMM: C = act(A[M,K] @ Bt[N,K]^T + bias [+pos]) ----------------
// BM=128, BK=32, 256 threads = 4 waves (2x2), wave tile 64 x BN/2.
// XCD-aware swizzle: contiguous (row-strip x all-cols) ranges per XCD for L2 A-reuse.
// OUT_MODE: 0 = f32, 1 = f16, 2 = dual. pos: optional [1024][N] add (patch embed).
template<int BN, int OUT_MODE, int ACT>
__global__ __launch_bounds__(256) void gemm_h(const _Float16* __restrict__ A,
        const _Float16* __restrict__ Bt, const float* __restrict__ bias,
        const float* __restrict__ pos, float* __restrict__ C32,
        _Float16* __restrict__ C16, int M, int N, int K)
{
    constexpr int WN  = BN / 2;
    constexpr int FN  = WN / 16;
    constexpr int NBJ = BN / 64;
    __shared__ _Float16 Al[128 * 32];
    __shared__ _Float16 Bl[BN * 32];

    const int tid  = threadIdx.x;
    const int wave = tid >> 6;
    const int lane = tid & 63;
    const int wr   = wave >> 1;
    const int wc   = wave & 1;
    const int lr   = lane & 15;
    const int quad = lane >> 4;

    // XCD swizzle (dispatch round-robins linear id over 8 XCDs)
    const int gx = gridDim.x, nb = gx * gridDim.y;
    int bx = blockIdx.x, by = blockIdx.y;
    if (!(nb & 7)) {
        int id  = by * gx + bx;
        int id2 = (id & 7) * (nb >> 3) + (id >> 3);
        by = id2 / gx; bx = id2 % gx;
    }
    const int row0 = by * 128;
    const int col0 = bx * BN;

    const int srow = lane >> 2;
    const int skof = (lane & 3) * 8;

    float4v acc[4][FN];
    #pragma unroll
    for (int i = 0; i < 4; ++i)
        #pragma unroll
        for (int j = 0; j < FN; ++j) {
            float4v z = {0.f, 0.f, 0.f, 0.f};
            acc[i][j] = z;
        }

    for (int k0 = 0; k0 < K; k0 += 32) {
        __syncthreads();
        #pragma unroll
        for (int j = 0; j < 2; ++j)
            async16(A + (size_t)(row0 + j * 64 + wave * 16 + srow) * K + k0 + skof,
                    &Al[(j * 64 + wave * 16) * 32]);
        #pragma unroll
        for (int j = 0; j < NBJ; ++j)
            async16(Bt + (size_t)(col0 + j * 64 + wave * 16 + srow) * K + k0 + skof,
                    &Bl[(j * 64 + wave * 16) * 32]);
        __syncthreads();

        half8 af[4], bf[FN];
        #pragma unroll
        for (int i = 0; i < 4; ++i)
            af[i] = *(const half8*)&Al[(wr * 64 + i * 16 + lr) * 32 + quad * 8];
        #pragma unroll
        for (int j = 0; j < FN; ++j)
            bf[j] = *(const half8*)&Bl[(wc * WN + j * 16 + lr) * 32 + quad * 8];
        #pragma unroll
        for (int i = 0; i < 4; ++i)
            #pragma unroll
            for (int j = 0; j < FN; ++j)
                acc[i][j] = __builtin_amdgcn_mfma_f32_16x16x32_f16(af[i], bf[j], acc[i][j], 0, 0, 0);
    }

    #pragma unroll
    for (int j = 0; j < FN; ++j) {
        int col = col0 + wc * WN + j * 16 + lr;
        float bj = bias[col];
        #pragma unroll
        for (int i = 0; i < 4; ++i) {
            int row = row0 + wr * 64 + i * 16 + quad * 4;
            #pragma unroll
            for (int r = 0; r < 4; ++r) {
                float v = acc[i][j][r] + bj;
                if (pos) v += pos[(size_t)((row + r) & 1023) * N + col];
                if (ACT) v = gelu_f(v);
                size_t gi = (size_t)(row + r) * N + col;
                if (OUT_MODE == 0 || OUT_MODE == 2) C32[gi] = v;
                if (OUT_MODE == 1 || OUT_MODE == 2) C16[gi] = (_Float16)v;
            }
        }
    }
}

// ---------------- head output scatter (pixel shuffle) ----------------
__global__ __launch_bounds__(256) void scatter_head(const float* __restrict__ h2,
        float* __restrict__ out, int f)
{
    int idx = blockIdx.x * 256 + threadIdx.x;     // 0 .. 262143
    int pq  = idx & 63;
    int tok = idx >> 6;
    int wp  = tok & 31;
    int hp  = (tok >> 5) & 31;
    int b   = tok >> 10;
    int p = pq >> 3, q = pq & 7;
    out[((b * 256 + hp * 8 + p) * 256 + wp * 8 + q) * 4 + f] = h2[idx];
}

// ---------------- launch ----------------
extern "C" void kernel_launch(void* const* d_in, const int* in_sizes, int n_in,
                              void* d_out, int out_size, void* d_ws, size_t ws_size,
                              hipStream_t stream) {
    const float* x        = (const float*)d_in[0];
    const float* grd      = (const float*)d_in[1];
    const float* conv_w   = (const float*)d_in[2];
    const float* conv_b   = (const float*)d_in[3];
    const float* pos_emb  = (const float*)d_in[4];
    const float* w1       = (const float*)d_in[5];
    const float* b1       = (const float*)d_in[6];
    const float* w2       = (const float*)d_in[7];
    const float* b2       = (const float*)d_in[8];
    const float* fc1_w    = (const float*)d_in[9];
    const float* fc1_b    = (const float*)d_in[10];
    const float* fc2_w    = (const float*)d_in[11];
    const float* fc2_b    = (const float*)d_in[12];
    const float* head_w1  = (const float*)d_in[13];
    const float* head_b1  = (const float*)d_in[14];
    const float* head_w2  = (const float*)d_in[15];
    const float* head_b2  = (const float*)d_in[16];
    float* out = (float*)d_out;
    float* ws  = (float*)d_ws;

    // ---- workspace layout, ALL sizes in float units (f16 count / 2) ----
    float* pf = ws;
    float* t        = pf;              pf += 3145728;   // 4096x768 fp32
    float* h2       = pf;              pf += 262144;    // 4096x64 fp32
    _Float16* t_h     = (_Float16*)pf; pf += 1572864;   // 4096x768 f16   (3,145,728 h)
    _Float16* convw_h = (_Float16*)pf; pf += 294912;    // 768x768 f16    (589,824 h)
    _Float16* Wsp     = (_Float16*)pf; pf += 589824;    // 128x9216 f16   (1,179,648 h)
    _Float16* hr_h    = (_Float16*)pf; pf += 835584;    // 2176x768 f16   (1,671,168 h)
    _Float16* hi_h    = (_Float16*)pf; pf += 835584;
    _Float16* h1t     = (_Float16*)pf; pf += 589824;    // 768x1536 f16   (1,179,648 h)
    _Float16* h2t     = (_Float16*)pf; pf += 49152;     // 1536x64 f16    (98,304 h)
    float* xr       = pf;              pf += 1671168;   // 2176x768 fp32 x4
    float* xi       = pf;              pf += 1671168;
    float* o1r      = pf;              pf += 1671168;
    float* o1i      = pf;              pf += 1671168;
    // hid_h (4096x3072 f16 = 6,291,456 f) aliases xr..o1i (6,684,672 f):
    // live only fc1->fc2 and head1->head2, when all DFT buffers are dead.
    _Float16* hid_h   = (_Float16*)xr;
    _Float16* WtAll   = (_Float16*)pf;                  // fallback: 2 slots; full: 8 slots
    _Float16* A_h     = t_h;                            // prepass-only alias
    // base = 14,860,288 f (59.4 MB); fallback +2,359,296 f = 68.9 MB (< 89.3 proven);
    // full  +9,437,184 f = 97.2 MB, gated on ws_size.
    size_t base_f = (size_t)(pf - ws);
    bool   full   = ws_size >= (base_f + 8ull * 1179648ull) * 4ull;

    // ---- prepass: weight prep + patch embed (MFMA) ----
    prep_specw<<<dim3(128), 256, 0, stream>>>(w1, w2, Wsp);
    cvt_f16<<<dim3(576), 256, 0, stream>>>(conv_w, convw_h);
    cvt_transpose<<<dim3(24, 48), 256, 0, stream>>>(head_w1, h1t, 768, 1536);
    cvt_transpose<<<dim3(48, 2), 256, 0, stream>>>(head_w2, h2t, 1536, 64);
    if (full) {
        for (int d = 0; d < 4; ++d) {
            cvt_transpose<<<dim3(24, 96), 256, 0, stream>>>(
                fc1_w + (size_t)d * 2359296, WtAll + (size_t)(2 * d) * 2359296, 768, 3072);
            cvt_transpose<<<dim3(96, 24), 256, 0, stream>>>(
                fc2_w + (size_t)d * 2359296, WtAll + (size_t)(2 * d + 1) * 2359296, 3072, 768);
        }
    }
    gather_patch<<<dim3(12288), 256, 0, stream>>>(x, grd, A_h);
    gemm_h<128, 0, 0><<<dim3(6, 32), 256, 0, stream>>>(
        A_h, convw_h, conv_b, pos_emb, t, nullptr, 4096, 768, 768);

    for (int f = 0; f < 4; ++f) {
        for (int d = 0; d < 4; ++d) {
            // rfft2 (ortho, 1/32 folded into fwd-W pass)
            dft_fwd_w<<<dim3(128, 3), 256, 0, stream>>>(t, o1r, o1i);
            dft_h<0><<<dim3(68, 3), 256, 0, stream>>>(o1r, o1i, xr, xi);
            // block-diag complex MLP via MFMA
            spec_mfma<0, 0><<<dim3(34, 8), 256, 0, stream>>>(
                xr, xi,
                Wsp + (size_t)((d * 2 + 0) * 2 + 0) * 73728,
                Wsp + (size_t)((d * 2 + 0) * 2 + 1) * 73728,
                b1 + d * 1536, b1 + d * 1536 + 768, hr_h, hi_h);
            spec_mfma<1, 1><<<dim3(34, 8), 256, 0, stream>>>(
                hr_h, hi_h,
                Wsp + (size_t)((d * 2 + 1) * 2 + 0) * 73728,
                Wsp + (size_t)((d * 2 + 1) * 2 + 1) * 73728,
                b2 + d * 1536, b2 + d * 1536 + 768, xr, xi);
            // irfft2 + residual (dual fp32/f16 write)
            dft_h<1><<<dim3(68, 3), 256, 0, stream>>>(xr, xi, o1r, o1i);
            dft_inv_w<<<dim3(128, 3), 256, 0, stream>>>(o1r, o1i, t, t_h);

            // channel MLP 768 -> 3072 -> 768 via fp16 MFMA (hid_h aliases dead DFT bufs)
            _Float16* Wt1 = full ? WtAll + (size_t)(2 * d) * 2359296     : WtAll;
            _Float16* Wt2 = full ? WtAll + (size_t)(2 * d + 1) * 2359296 : WtAll + 2359296;
            if (!full) {
                cvt_transpose<<<dim3(24, 96), 256, 0, stream>>>(fc1_w + (size_t)d * 2359296, Wt1, 768, 3072);
                cvt_transpose<<<dim3(96, 24), 256, 0, stream>>>(fc2_w + (size_t)d * 2359296, Wt2, 3072, 768);
            }
            gemm_h<128, 1, 1><<<dim3(24, 32), 256, 0, stream>>>(
                t_h, Wt1, fc1_b + d * 3072, nullptr, nullptr, hid_h, 4096, 3072, 768);
            gemm_h<64, 2, 0><<<dim3(12, 32), 256, 0, stream>>>(
                hid_h, Wt2, fc2_b + d * 768, nullptr, t, t_h, 4096, 768, 3072);
        }
        // head on current state (t_h mirrors t)
        gemm_h<128, 1, 1><<<dim3(12, 32), 256, 0, stream>>>(
            t_h, h1t, head_b1, nullptr, nullptr, hid_h, 4096, 1536, 768);
        gemm_h<64, 0, 0><<<dim3(1, 32), 256, 0, stream>>>(
            hid_h, h2t, head_b2, nullptr, h2, nullptr, 4096, 64, 1536);
        scatter_head<<<dim3(1024), 256, 0, stream>>>(h2, out, f);
    }
}

// Round 6
// 4464.068 us; speedup vs baseline: 1.0458x; 1.0458x over previous
//
#include <hip/hip_runtime.h>
#include <hip/hip_bf16.h>
#include <math.h>

// ---------------- static config ----------------
// B=4, H=W=256, TIN=10, F=4, P=8, CIN=12, E=768, NB=8, BS=96,
// HP=WP=32, MID=3072, DEPTH=4, LAM=0.01, WF=17, TOK=4096, POS=B*32*17=2176

typedef __attribute__((ext_vector_type(8))) _Float16 half8;
typedef __attribute__((ext_vector_type(4))) _Float16 half4v;
typedef __attribute__((ext_vector_type(4))) float float4v;

__device__ __forceinline__ float gelu_f(float v) {
    return 0.5f * v * (1.0f + erff(v * 0.70710678118654752f));
}
__device__ __forceinline__ float shrink_f(float v) {
    return (v > 0.01f) ? (v - 0.01f) : ((v < -0.01f) ? (v + 0.01f) : 0.0f);
}

#define STEP32 0.19634954084936207f  // 2*pi/32

// async 16B global->LDS (lds dest wave-uniform; HW adds lane*16)
__device__ __forceinline__ void async16(const void* g, void* l) {
    __builtin_amdgcn_global_load_lds(
        (const __attribute__((address_space(1))) unsigned int*)g,
        (__attribute__((address_space(3))) unsigned int*)l, 16, 0, 0);
}

// ---------------- gather patches into A_h [4096][768] f16 ----------------
__global__ __launch_bounds__(256) void gather_patch(const float* __restrict__ x,
        const float* __restrict__ grd, _Float16* __restrict__ A)
{
    int idx = blockIdx.x * 256 + threadIdx.x;     // 0 .. 3,145,727
    int j   = idx % 768;
    int tok = idx / 768;
    int c = j >> 6, p = (j >> 3) & 7, q = j & 7;
    int wp = tok & 31, hp = (tok >> 5) & 31, b = tok >> 10;
    int hh = hp * 8 + p, ww = wp * 8 + q;
    float v;
    if (c < 10) v = x[((b * 256 + hh) * 256 + ww) * 10 + c];
    else        v = grd[((b * 256 + hh) * 256 + ww) * 2 + (c - 10)];
    A[idx] = (_Float16)v;
}

// ---------------- forward DFT along W (real fp32 -> 17 complex f16), scale 1/32 ----------------
__global__ __launch_bounds__(256) void dft_fwd_w(const float* __restrict__ t,
        _Float16* __restrict__ Xr, _Float16* __restrict__ Xi)
{
    __shared__ float2 lut[32];
    int bh = blockIdx.x;            // b*32 + h
    int tid = threadIdx.x;
    if (tid < 32) { float a = tid * STEP32; lut[tid] = make_float2(cosf(a), sinf(a)); }
    __syncthreads();
    int c = blockIdx.y * 256 + tid;
    float v[32];
    #pragma unroll
    for (int w = 0; w < 32; ++w) v[w] = t[(bh * 32 + w) * 768 + c];
    for (int kw = 0; kw <= 16; ++kw) {
        float ar = 0.f, ai = 0.f;
        #pragma unroll
        for (int w = 0; w < 32; ++w) {
            float2 cs = lut[(kw * w) & 31];
            ar += v[w] * cs.x;
            ai -= v[w] * cs.y;
        }
        Xr[(bh * 17 + kw) * 768 + c] = (_Float16)(ar * 0.03125f);
        Xi[(bh * 17 + kw) * 768 + c] = (_Float16)(ai * 0.03125f);
    }
}

// ---------------- complex DFT along H (f16 I/O, fp32 compute) ----------------
template<int INV>
__global__ __launch_bounds__(256) void dft_h(const _Float16* __restrict__ inR,
        const _Float16* __restrict__ inI,
        _Float16* __restrict__ outR, _Float16* __restrict__ outI)
{
    __shared__ float2 lut[32];
    int bk = blockIdx.x;            // b*17 + kw
    int b = bk / 17, kw = bk % 17;
    int tid = threadIdx.x;
    if (tid < 32) { float a = tid * STEP32; lut[tid] = make_float2(cosf(a), sinf(a)); }
    __syncthreads();
    int c = blockIdx.y * 256 + tid;
    float cr[32], ci[32];
    #pragma unroll
    for (int h = 0; h < 32; ++h) {
        cr[h] = (float)inR[((b * 32 + h) * 17 + kw) * 768 + c];
        ci[h] = (float)inI[((b * 32 + h) * 17 + kw) * 768 + c];
    }
    for (int kh = 0; kh < 32; ++kh) {
        float ar = 0.f, ai = 0.f;
        #pragma unroll
        for (int h = 0; h < 32; ++h) {
            float2 cs = lut[(kh * h) & 31];
            if (INV) { ar += cr[h] * cs.x - ci[h] * cs.y; ai += ci[h] * cs.x + cr[h] * cs.y; }
            else     { ar += cr[h] * cs.x + ci[h] * cs.y; ai += ci[h] * cs.x - cr[h] * cs.y; }
        }
        outR[((b * 32 + kh) * 17 + kw) * 768 + c] = (_Float16)ar;
        outI[((b * 32 + kh) * 17 + kw) * 768 + c] = (_Float16)ai;
    }
}

// ---------------- inverse DFT along W (f16 in) + residual; dual fp32/f16 write ----------------
__global__ __launch_bounds__(256) void dft_inv_w(const _Float16* __restrict__ Yr,
        const _Float16* __restrict__ Yi,
        float* __restrict__ t, _Float16* __restrict__ t_h)
{
    __shared__ float2 lut[32];
    int bh = blockIdx.x;
    int tid = threadIdx.x;
    if (tid < 32) { float a = tid * STEP32; lut[tid] = make_float2(cosf(a), sinf(a)); }
    __syncthreads();
    int c = blockIdx.y * 256 + tid;
    float yr[17], yi[16];
    #pragma unroll
    for (int k = 0; k <= 16; ++k) yr[k] = (float)Yr[(bh * 17 + k) * 768 + c];
    #pragma unroll
    for (int k = 1; k <= 15; ++k) yi[k] = (float)Yi[(bh * 17 + k) * 768 + c];
    for (int w = 0; w < 32; ++w) {
        float val = yr[0] + ((w & 1) ? -yr[16] : yr[16]);
        #pragma unroll
        for (int k = 1; k <= 15; ++k) {
            float2 cs = lut[(k * w) & 31];
            val += 2.f * (yr[k] * cs.x - yi[k] * cs.y);
        }
        int gi = (bh * 32 + w) * 768 + c;
        float r = val * 0.03125f + t[gi];
        t[gi] = r;
        t_h[gi] = (_Float16)r;
    }
}

// ---------------- spectral weight prep: [i][o] fp32 -> [o][i] f16, 128 matrices ----------------
__global__ __launch_bounds__(256) void prep_specw(const float* __restrict__ w1,
        const float* __restrict__ w2, _Float16* __restrict__ out)
{
    __shared__ float tile[96][97];
    int mid = blockIdx.x;
    int n  = mid & 7;
    int ri = (mid >> 3) & 1;
    int l  = (mid >> 4) & 1;
    int d  = mid >> 5;
    const float* src = (l ? w2 : w1) + ((size_t)(d * 2 + ri) * 8 + n) * 9216;
    for (int idx = threadIdx.x; idx < 9216; idx += 256)
        tile[idx / 96][idx % 96] = src[idx];
    __syncthreads();
    _Float16* dst = out + (size_t)mid * 9216;
    for (int idx = threadIdx.x; idx < 9216; idx += 256)
        dst[idx] = (_Float16)tile[idx % 96][idx / 96];   // dst[o][i] = src[i][o]
}

// ---------------- spectral block-diag complex MFMA layer (f16 in/out) ----------------
// ACT 0: gelu; ACT 1: softshrink
template<int ACT>
__global__ __launch_bounds__(256) void spec_mfma(
        const _Float16* __restrict__ inR, const _Float16* __restrict__ inI,
        const _Float16* __restrict__ WtR, const _Float16* __restrict__ WtI,
        const float* __restrict__ bR, const float* __restrict__ bI,
        _Float16* __restrict__ outR, _Float16* __restrict__ outI)
{
    const int n   = blockIdx.y;
    const int m0  = blockIdx.x * 64;
    const int tid = threadIdx.x;
    const int wave = tid >> 6, lane = tid & 63;
    const int wr = wave >> 1, wc = wave & 1;
    const int lr = lane & 15, quad = lane >> 4;

    float4v accR[2][3], accI[2][3];
    #pragma unroll
    for (int i = 0; i < 2; ++i)
        #pragma unroll
        for (int j = 0; j < 3; ++j) {
            float4v z = {0.f, 0.f, 0.f, 0.f};
            accR[i][j] = z; accI[i][j] = z;
        }

    const _Float16* wRb = WtR + (size_t)n * 9216;
    const _Float16* wIb = WtI + (size_t)n * 9216;

    #pragma unroll
    for (int kc = 0; kc < 3; ++kc) {
        half8 aR[2], aI[2], aIn[2];
        #pragma unroll
        for (int i = 0; i < 2; ++i) {
            size_t off = (size_t)(m0 + wr * 32 + i * 16 + lr) * 768 + n * 96 + kc * 32 + quad * 8;
            aR[i] = *(const half8*)(inR + off);
            aI[i] = *(const half8*)(inI + off);
            aIn[i] = -aI[i];
        }
        half8 bRf[3], bIf[3];
        #pragma unroll
        for (int j = 0; j < 3; ++j) {
            int o = wc * 48 + j * 16 + lr;
            bRf[j] = *(const half8*)&wRb[o * 96 + kc * 32 + quad * 8];
            bIf[j] = *(const half8*)&wIb[o * 96 + kc * 32 + quad * 8];
        }
        #pragma unroll
        for (int i = 0; i < 2; ++i)
            #pragma unroll
            for (int j = 0; j < 3; ++j) {
                accR[i][j] = __builtin_amdgcn_mfma_f32_16x16x32_f16(aR[i],  bRf[j], accR[i][j], 0, 0, 0);
                accR[i][j] = __builtin_amdgcn_mfma_f32_16x16x32_f16(aIn[i], bIf[j], accR[i][j], 0, 0, 0);
                accI[i][j] = __builtin_amdgcn_mfma_f32_16x16x32_f16(aI[i],  bRf[j], accI[i][j], 0, 0, 0);
                accI[i][j] = __builtin_amdgcn_mfma_f32_16x16x32_f16(aR[i],  bIf[j], accI[i][j], 0, 0, 0);
            }
    }

    #pragma unroll
    for (int j = 0; j < 3; ++j) {
        int ol = wc * 48 + j * 16 + lr;
        float br = bR[n * 96 + ol], bi = bI[n * 96 + ol];
        #pragma unroll
        for (int i = 0; i < 2; ++i) {
            int rowb = m0 + wr * 32 + i * 16 + quad * 4;
            #pragma unroll
            for (int r = 0; r < 4; ++r) {
                float vr = accR[i][j][r] + br;
                float vi = accI[i][j][r] + bi;
                size_t gi = (size_t)(rowb + r) * 768 + n * 96 + ol;
                if (ACT == 0) {
                    outR[gi] = (_Float16)gelu_f(vr);
                    outI[gi] = (_Float16)gelu_f(vi);
                } else {
                    outR[gi] = (_Float16)shrink_f(vr);
                    outI[gi] = (_Float16)shrink_f(vi);
                }
            }
        }
    }
}

// ---------------- f32 -> f16 elementwise (vectorized x4) ----------------
__global__ __launch_bounds__(256) void cvt_f16(const float* __restrict__ in,
        _Float16* __restrict__ out)
{
    int i = blockIdx.x * 256 + threadIdx.x;
    float4 v = ((const float4*)in)[i];
    half4v o;
    o.x = (_Float16)v.x; o.y = (_Float16)v.y; o.z = (_Float16)v.z; o.w = (_Float16)v.w;
    ((half4v*)out)[i] = o;
}

// ---------------- f32 [K][N] -> f16 [N][K] transpose ----------------
__global__ __launch_bounds__(256) void cvt_transpose(const float* __restrict__ in,
        _Float16* __restrict__ out, int K, int N)
{
    __shared__ float tile[32][33];
    int kb = blockIdx.x * 32, nb = blockIdx.y * 32;
    int tx = threadIdx.x & 31, ty = threadIdx.x >> 5;   // ty 0..7
    #pragma unroll
    for (int r = 0; r < 32; r += 8)
        tile[ty + r][tx] = in[(size_t)(kb + ty + r) * N + nb + tx];
    __syncthreads();
    #pragma unroll
    for (int r = 0; r < 32; r += 8)
        out[(size_t)(nb + ty + r) * K + kb + tx] = (_Float16)tile[tx][ty + r];
}

// ---------------- fp16 MFMA GEMM, double-buffered LDS ----------------
// C = act(A[M,K] @ Bt[N,K]^T + bias [+pos]); BM=128, BK=32, 256 thr = 4 waves 2x2.
// Stage-after-barrier pipeline: tile k+1 loads overlap compute(k); 1 barrier/iter.
// XCD-aware swizzle. OUT_MODE: 0 = f32, 1 = f16, 2 = dual.
template<int BN, int OUT_MODE, int ACT>
__global__ __launch_bounds__(256) void gemm_h(const _Float16* __restrict__ A,
        const _Float16* __restrict__ Bt, const float* __restrict__ bias,
        const float* __restrict__ pos, float* __restrict__ C32,
        _Float16* __restrict__ C16, int M, int N, int K)
{
    constexpr int WN  = BN / 2;
    constexpr int FN  = WN / 16;
    constexpr int NBJ = BN / 64;
    __shared__ _Float16 Al[2][128 * 32];
    __shared__ _Float16 Bl[2][BN * 32];

    const int tid  = threadIdx.x;
    const int wave = tid >> 6;
    const int lane = tid & 63;
    const int wr   = wave >> 1;
    const int wc   = wave & 1;
    const int lr   = lane & 15;
    const int quad = lane >> 4;

    // XCD swizzle (dispatch round-robins linear id over 8 XCDs)
    const int gx = gridDim.x, nb = gx * gridDim.y;
    int bx = blockIdx.x, by = blockIdx.y;
    if (!(nb & 7)) {
        int id  = by * gx + bx;
        int id2 = (id & 7) * (nb >> 3) + (id >> 3);
        by = id2 / gx; bx = id2 % gx;
    }
    const int row0 = by * 128;
    const int col0 = bx * BN;

    const int srow = lane >> 2;
    const int skof = (lane & 3) * 8;

    auto stage = [&](int b, int k0) {
        #pragma unroll
        for (int j = 0; j < 2; ++j)
            async16(A + (size_t)(row0 + j * 64 + wave * 16 + srow) * K + k0 + skof,
                    &Al[b][(j * 64 + wave * 16) * 32]);
        #pragma unroll
        for (int j = 0; j < NBJ; ++j)
            async16(Bt + (size_t)(col0 + j * 64 + wave * 16 + srow) * K + k0 + skof,
                    &Bl[b][(j * 64 + wave * 16) * 32]);
    };

    float4v acc[4][FN];
    #pragma unroll
    for (int i = 0; i < 4; ++i)
        #pragma unroll
        for (int j = 0; j < FN; ++j) {
            float4v z = {0.f, 0.f, 0.f, 0.f};
            acc[i][j] = z;
        }

    const int KT = K >> 5;
    stage(0, 0);
    for (int kt = 0; kt < KT; ++kt) {
        __syncthreads();                       // drains stage(kt) loads (issued last iter)
        if (kt + 1 < KT) stage((kt + 1) & 1, (kt + 1) << 5);  // overlaps compute below
        const int cb = kt & 1;
        half8 af[4], bf[FN];
        #pragma unroll
        for (int i = 0; i < 4; ++i)
            af[i] = *(const half8*)&Al[cb][(wr * 64 + i * 16 + lr) * 32 + quad * 8];
        #pragma unroll
        for (int j = 0; j < FN; ++j)
            bf[j] = *(const half8*)&Bl[cb][(wc * WN + j * 16 + lr) * 32 + quad * 8];
        #pragma unroll
        for (int i = 0; i < 4; ++i)
            #pragma unroll
            for (int j = 0; j < FN; ++j)
                acc[i][j] = __builtin_amdgcn_mfma_f32_16x16x32_f16(af[i], bf[j], acc[i][j], 0, 0, 0);
    }

    #pragma unroll
    for (int j = 0; j < FN; ++j) {
        int col = col0 + wc * WN + j * 16 + lr;
        float bj = bias[col];
        #pragma unroll
        for (int i = 0; i < 4; ++i) {
            int row = row0 + wr * 64 + i * 16 + quad * 4;
            #pragma unroll
            for (int r = 0; r < 4; ++r) {
                float v = acc[i][j][r] + bj;
                if (pos) v += pos[(size_t)((row + r) & 1023) * N + col];
                if (ACT) v = gelu_f(v);
                size_t gi = (size_t)(row + r) * N + col;
                if (OUT_MODE == 0 || OUT_MODE == 2) C32[gi] = v;
                if (OUT_MODE == 1 || OUT_MODE == 2) C16[gi] = (_Float16)v;
            }
        }
    }
}

// ---------------- head output scatter (pixel shuffle) ----------------
__global__ __launch_bounds__(256) void scatter_head(const float* __restrict__ h2,
        float* __restrict__ out, int f)
{
    int idx = blockIdx.x * 256 + threadIdx.x;     // 0 .. 262143
    int pq  = idx & 63;
    int tok = idx >> 6;
    int wp  = tok & 31;
    int hp  = (tok >> 5) & 31;
    int b   = tok >> 10;
    int p = pq >> 3, q = pq & 7;
    out[((b * 256 + hp * 8 + p) * 256 + wp * 8 + q) * 4 + f] = h2[idx];
}

// ---------------- launch ----------------
extern "C" void kernel_launch(void* const* d_in, const int* in_sizes, int n_in,
                              void* d_out, int out_size, void* d_ws, size_t ws_size,
                              hipStream_t stream) {
    const float* x        = (const float*)d_in[0];
    const float* grd      = (const float*)d_in[1];
    const float* conv_w   = (const float*)d_in[2];
    const float* conv_b   = (const float*)d_in[3];
    const float* pos_emb  = (const float*)d_in[4];
    const float* w1       = (const float*)d_in[5];
    const float* b1       = (const float*)d_in[6];
    const float* w2       = (const float*)d_in[7];
    const float* b2       = (const float*)d_in[8];
    const float* fc1_w    = (const float*)d_in[9];
    const float* fc1_b    = (const float*)d_in[10];
    const float* fc2_w    = (const float*)d_in[11];
    const float* fc2_b    = (const float*)d_in[12];
    const float* head_w1  = (const float*)d_in[13];
    const float* head_b1  = (const float*)d_in[14];
    const float* head_w2  = (const float*)d_in[15];
    const float* head_b2  = (const float*)d_in[16];
    float* out = (float*)d_out;
    float* ws  = (float*)d_ws;

    // ---- workspace layout, ALL sizes in float units; total 22,233,088 f = 88.9 MB ----
    float* pf = ws;
    float* t        = pf;              pf += 3145728;   // 4096x768 fp32
    float* h2       = pf;              pf += 262144;    // 4096x64 fp32
    _Float16* t_h     = (_Float16*)pf; pf += 1572864;   // 4096x768 f16
    _Float16* Wsp     = (_Float16*)pf; pf += 589824;    // 128x9216 f16 spectral weights
    _Float16* h1t     = (_Float16*)pf; pf += 589824;    // 768x1536 -> [1536][768] f16
    _Float16* h2t     = (_Float16*)pf; pf += 49152;     // 1536x64 -> [64][1536] f16
    _Float16* convw_h = (_Float16*)pf; pf += 294912;    // 768x768 f16 (prepass only)
    // ALIAS region: hid_h (4096x3072 f16 = 6,291,456 f) over 3 spectral f16 pairs
    // (6 x 835,584 f = 5,013,504 f). Disjoint live ranges: hid only fc1->fc2 / head1->head2.
    float* alias    = pf;              pf += 6291456;
    _Float16* hid_h = (_Float16*)alias;
    _Float16* xa_r  = (_Float16*)(alias);
    _Float16* xa_i  = (_Float16*)(alias + 835584);
    _Float16* xb_r  = (_Float16*)(alias + 1671168);
    _Float16* xb_i  = (_Float16*)(alias + 2506752);
    _Float16* xc_r  = (_Float16*)(alias + 3342336);
    _Float16* xc_i  = (_Float16*)(alias + 4177920);
    _Float16* WtAll = (_Float16*)pf;   pf += 9437184;   // 8 x [N][K] fc weights f16
    _Float16* A_h   = t_h;                              // prepass-only alias

    // ---- prepass: weight prep + patch embed (MFMA) ----
    prep_specw<<<dim3(128), 256, 0, stream>>>(w1, w2, Wsp);
    cvt_f16<<<dim3(576), 256, 0, stream>>>(conv_w, convw_h);
    cvt_transpose<<<dim3(24, 48), 256, 0, stream>>>(head_w1, h1t, 768, 1536);
    cvt_transpose<<<dim3(48, 2), 256, 0, stream>>>(head_w2, h2t, 1536, 64);
    for (int d = 0; d < 4; ++d) {
        cvt_transpose<<<dim3(24, 96), 256, 0, stream>>>(
            fc1_w + (size_t)d * 2359296, WtAll + (size_t)(2 * d) * 2359296, 768, 3072);
        cvt_transpose<<<dim3(96, 24), 256, 0, stream>>>(
            fc2_w + (size_t)d * 2359296, WtAll + (size_t)(2 * d + 1) * 2359296, 3072, 768);
    }
    gather_patch<<<dim3(12288), 256, 0, stream>>>(x, grd, A_h);
    gemm_h<128, 0, 0><<<dim3(6, 32), 256, 0, stream>>>(
        A_h, convw_h, conv_b, pos_emb, t, nullptr, 4096, 768, 768);

    for (int f = 0; f < 4; ++f) {
        for (int d = 0; d < 4; ++d) {
            // rfft2 (ortho, 1/32 folded into fwd-W pass); intermediates f16
            dft_fwd_w<<<dim3(128, 3), 256, 0, stream>>>(t, xa_r, xa_i);
            dft_h<0><<<dim3(68, 3), 256, 0, stream>>>(xa_r, xa_i, xb_r, xb_i);
            // block-diag complex MLP via MFMA
            spec_mfma<0><<<dim3(34, 8), 256, 0, stream>>>(
                xb_r, xb_i,
                Wsp + (size_t)((d * 2 + 0) * 2 + 0) * 73728,
                Wsp + (size_t)((d * 2 + 0) * 2 + 1) * 73728,
                b1 + d * 1536, b1 + d * 1536 + 768, xc_r, xc_i);
            spec_mfma<1><<<dim3(34, 8), 256, 0, stream>>>(
                xc_r, xc_i,
                Wsp + (size_t)((d * 2 + 1) * 2 + 0) * 73728,
                Wsp + (size_t)((d * 2 + 1) * 2 + 1) * 73728,
                b2 + d * 1536, b2 + d * 1536 + 768, xa_r, xa_i);
            // irfft2 + residual (dual fp32/f16 write)
            dft_h<1><<<dim3(68, 3), 256, 0, stream>>>(xa_r, xa_i, xb_r, xb_i);
            dft_inv_w<<<dim3(128, 3), 256, 0, stream>>>(xb_r, xb_i, t, t_h);
            // channel MLP 768 -> 3072 -> 768 via fp16 MFMA (hid_h aliases dead spectral bufs)
            gemm_h<128, 1, 1><<<dim3(24, 32), 256, 0, stream>>>(
                t_h, WtAll + (size_t)(2 * d) * 2359296, fc1_b + d * 3072,
                nullptr, nullptr, hid_h, 4096, 3072, 768);
            gemm_h<64, 2, 0><<<dim3(12, 32), 256, 0, stream>>>(
                hid_h, WtAll + (size_t)(2 * d + 1) * 2359296, fc2_b + d * 768,
                nullptr, t, t_h, 4096, 768, 3072);
        }
        // head on current state (t_h mirrors t)
        gemm_h<128, 1, 1><<<dim3(12, 32), 256, 0, stream>>>(
            t_h, h1t, head_b1, nullptr, nullptr, hid_h, 4096, 1536, 768);
        gemm_h<64, 0, 0><<<dim3(1, 32), 256, 0, stream>>>(
            hid_h, h2t, head_b2, nullptr, h2, nullptr, 4096, 64, 1536);
        scatter_head<<<dim3(1024), 256, 0, stream>>>(h2, out, f);
    }
}

// Round 7
// 3078.713 us; speedup vs baseline: 1.5163x; 1.4500x over previous
//
#include <hip/hip_runtime.h>
#include <hip/hip_bf16.h>
#include <math.h>

// ---------------- static config ----------------
// B=4, H=W=256, TIN=10, F=4, P=8, CIN=12, E=768, NB=8, BS=96,
// HP=WP=32, MID=3072, DEPTH=4, LAM=0.01, WF=17, TOK=4096, POS=B*32*17=2176

typedef __attribute__((ext_vector_type(8))) _Float16 half8;
typedef __attribute__((ext_vector_type(4))) _Float16 half4v;
typedef __attribute__((ext_vector_type(4))) float float4v;

__device__ __forceinline__ float gelu_f(float v) {
    return 0.5f * v * (1.0f + erff(v * 0.70710678118654752f));
}
__device__ __forceinline__ float shrink_f(float v) {
    return (v > 0.01f) ? (v - 0.01f) : ((v < -0.01f) ? (v + 0.01f) : 0.0f);
}

#define STEP32 0.19634954084936207f  // 2*pi/32

// async 16B global->LDS (lds dest wave-uniform; HW adds lane*16)
__device__ __forceinline__ void async16(const void* g, void* l) {
    __builtin_amdgcn_global_load_lds(
        (const __attribute__((address_space(1))) unsigned int*)g,
        (__attribute__((address_space(3))) unsigned int*)l, 16, 0, 0);
}

// ---------------- gather patches into A_h [4096][768] f16 ----------------
__global__ __launch_bounds__(256) void gather_patch(const float* __restrict__ x,
        const float* __restrict__ grd, _Float16* __restrict__ A)
{
    int idx = blockIdx.x * 256 + threadIdx.x;     // 0 .. 3,145,727
    int j   = idx % 768;
    int tok = idx / 768;
    int c = j >> 6, p = (j >> 3) & 7, q = j & 7;
    int wp = tok & 31, hp = (tok >> 5) & 31, b = tok >> 10;
    int hh = hp * 8 + p, ww = wp * 8 + q;
    float v;
    if (c < 10) v = x[((b * 256 + hh) * 256 + ww) * 10 + c];
    else        v = grd[((b * 256 + hh) * 256 + ww) * 2 + (c - 10)];
    A[idx] = (_Float16)v;
}

// ---------------- forward DFT along W (real fp32 -> 17 complex f16), scale 1/32 ----------------
__global__ __launch_bounds__(256) void dft_fwd_w(const float* __restrict__ t,
        _Float16* __restrict__ Xr, _Float16* __restrict__ Xi)
{
    __shared__ float2 lut[32];
    int bh = blockIdx.x;            // b*32 + h
    int tid = threadIdx.x;
    if (tid < 32) { float a = tid * STEP32; lut[tid] = make_float2(cosf(a), sinf(a)); }
    __syncthreads();
    int c = blockIdx.y * 256 + tid;
    float v[32];
    #pragma unroll
    for (int w = 0; w < 32; ++w) v[w] = t[(bh * 32 + w) * 768 + c];
    for (int kw = 0; kw <= 16; ++kw) {
        float ar = 0.f, ai = 0.f;
        #pragma unroll
        for (int w = 0; w < 32; ++w) {
            float2 cs = lut[(kw * w) & 31];
            ar += v[w] * cs.x;
            ai -= v[w] * cs.y;
        }
        Xr[(bh * 17 + kw) * 768 + c] = (_Float16)(ar * 0.03125f);
        Xi[(bh * 17 + kw) * 768 + c] = (_Float16)(ai * 0.03125f);
    }
}

// ---------------- inverse DFT along W (f16 in) + residual; dual fp32/f16 write ----------------
__global__ __launch_bounds__(256) void dft_inv_w(const _Float16* __restrict__ Yr,
        const _Float16* __restrict__ Yi,
        float* __restrict__ t, _Float16* __restrict__ t_h)
{
    __shared__ float2 lut[32];
    int bh = blockIdx.x;
    int tid = threadIdx.x;
    if (tid < 32) { float a = tid * STEP32; lut[tid] = make_float2(cosf(a), sinf(a)); }
    __syncthreads();
    int c = blockIdx.y * 256 + tid;
    float yr[17], yi[16];
    #pragma unroll
    for (int k = 0; k <= 16; ++k) yr[k] = (float)Yr[(bh * 17 + k) * 768 + c];
    #pragma unroll
    for (int k = 1; k <= 15; ++k) yi[k] = (float)Yi[(bh * 17 + k) * 768 + c];
    for (int w = 0; w < 32; ++w) {
        float val = yr[0] + ((w & 1) ? -yr[16] : yr[16]);
        #pragma unroll
        for (int k = 1; k <= 15; ++k) {
            float2 cs = lut[(k * w) & 31];
            val += 2.f * (yr[k] * cs.x - yi[k] * cs.y);
        }
        int gi = (bh * 32 + w) * 768 + c;
        float r = val * 0.03125f + t[gi];
        t[gi] = r;
        t_h[gi] = (_Float16)r;
    }
}

// ---------------- spectral weight prep: [i][o] fp32 -> [o][i] f16, 128 matrices ----------------
__global__ __launch_bounds__(256) void prep_specw(const float* __restrict__ w1,
        const float* __restrict__ w2, _Float16* __restrict__ out)
{
    __shared__ float tile[96][97];
    int mid = blockIdx.x;
    int n  = mid & 7;
    int ri = (mid >> 3) & 1;
    int l  = (mid >> 4) & 1;
    int d  = mid >> 5;
    const float* src = (l ? w2 : w1) + ((size_t)(d * 2 + ri) * 8 + n) * 9216;
    for (int idx = threadIdx.x; idx < 9216; idx += 256)
        tile[idx / 96][idx % 96] = src[idx];
    __syncthreads();
    _Float16* dst = out + (size_t)mid * 9216;
    for (int idx = threadIdx.x; idx < 9216; idx += 256)
        dst[idx] = (_Float16)tile[idx % 96][idx / 96];   // dst[o][i] = src[i][o]
}

// ---------------- fused spectral: H-DFT -> spec1(gelu) -> spec2(shrink) -> H-IDFT ----------------
// grid (68 = b*17+kw, 8 = n); 256 thr = 4 waves; wave tile: 16 rows (wr) x 48 cols (wc).
// All stages MFMA on LDS tiles; twiddle table (kh*h mod 32) symmetric -> serves DFT & IDFT.
__global__ __launch_bounds__(256) void spec_fused(
        const _Float16* __restrict__ Xr, const _Float16* __restrict__ Xi,
        const _Float16* __restrict__ W1r, const _Float16* __restrict__ W1i,
        const _Float16* __restrict__ W2r, const _Float16* __restrict__ W2i,
        const float* __restrict__ b1r, const float* __restrict__ b1i,
        const float* __restrict__ b2r, const float* __restrict__ b2i,
        _Float16* __restrict__ Yr, _Float16* __restrict__ Yi)
{
    __shared__ alignas(16) _Float16 Ec[1024], Es[1024];       // [m][k] twiddle, 32x32
    __shared__ alignas(16) _Float16 XTr[3840], XTi[3840];     // [c][h] pad40; reused as T2T[c][kh]
    __shared__ alignas(16) _Float16 Zr[3328], Zi[3328];       // [kh][c] pad104
    __shared__ alignas(16) _Float16 Sr[3328], Si[3328];       // [kh][o] pad104

    const int bk = blockIdx.x;       // b*17 + kw
    const int n  = blockIdx.y;
    const int tid = threadIdx.x;
    const int wave = tid >> 6, lane = tid & 63;
    const int wr = wave >> 1, wc = wave & 1;
    const int lr = lane & 15, quad = lane >> 4;
    const int b = bk / 17, kw = bk % 17;
    const size_t base0 = ((size_t)b * 544 + kw) * 768 + n * 96;   // +h*13056 +c

    // twiddle tables (f16)
    for (int i = tid; i < 1024; i += 256) {
        int kh = i >> 5, h = i & 31;
        float a = ((kh * h) & 31) * STEP32;
        Ec[i] = (_Float16)cosf(a);
        Es[i] = (_Float16)sinf(a);
    }
    // load X -> XT[c][h]
    for (int i = tid; i < 3072; i += 256) {
        int h = i / 96, c = i % 96;
        size_t g = base0 + (size_t)h * 13056 + c;
        XTr[c * 40 + h] = Xr[g];
        XTi[c * 40 + h] = Xi[g];
    }
    __syncthreads();

    const _Float16* w1r = W1r + (size_t)n * 9216;
    const _Float16* w1i = W1i + (size_t)n * 9216;
    const _Float16* w2r = W2r + (size_t)n * 9216;
    const _Float16* w2i = W2i + (size_t)n * 9216;

    // twiddle A-frags: row m = wr*16+lr, k = quad*8.. (valid for stage A m=kh and stage D m=h)
    half8 eC = *(const half8*)&Ec[(wr * 16 + lr) * 32 + quad * 8];
    half8 eS = *(const half8*)&Es[(wr * 16 + lr) * 32 + quad * 8];
    half8 eSn = -eS;

    // ---- stage A: Z[kh][c] = DFT_h(X); Zr = cos*Xr + sin*Xi ; Zi = cos*Xi - sin*Xr
    {
        float4v zr[3], zi[3];
        #pragma unroll
        for (int j = 0; j < 3; ++j) { float4v z = {0,0,0,0}; zr[j] = z; zi[j] = z; }
        #pragma unroll
        for (int j = 0; j < 3; ++j) {
            int c = wc * 48 + j * 16 + lr;
            half8 xr = *(const half8*)&XTr[c * 40 + quad * 8];
            half8 xi = *(const half8*)&XTi[c * 40 + quad * 8];
            zr[j] = __builtin_amdgcn_mfma_f32_16x16x32_f16(eC,  xr, zr[j], 0, 0, 0);
            zr[j] = __builtin_amdgcn_mfma_f32_16x16x32_f16(eS,  xi, zr[j], 0, 0, 0);
            zi[j] = __builtin_amdgcn_mfma_f32_16x16x32_f16(eC,  xi, zi[j], 0, 0, 0);
            zi[j] = __builtin_amdgcn_mfma_f32_16x16x32_f16(eSn, xr, zi[j], 0, 0, 0);
        }
        #pragma unroll
        for (int j = 0; j < 3; ++j) {
            int c = wc * 48 + j * 16 + lr;
            #pragma unroll
            for (int r = 0; r < 4; ++r) {
                int kh = wr * 16 + quad * 4 + r;
                Zr[kh * 104 + c] = (_Float16)zr[j][r];
                Zi[kh * 104 + c] = (_Float16)zi[j][r];
            }
        }
    }
    __syncthreads();

    // ---- stage B: S[kh][o] = gelu( Z @ W1 + b1 ) complex
    {
        float4v sr[3], si[3];
        #pragma unroll
        for (int j = 0; j < 3; ++j) { float4v z = {0,0,0,0}; sr[j] = z; si[j] = z; }
        #pragma unroll
        for (int kc = 0; kc < 3; ++kc) {
            half8 ar = *(const half8*)&Zr[(wr * 16 + lr) * 104 + kc * 32 + quad * 8];
            half8 ai = *(const half8*)&Zi[(wr * 16 + lr) * 104 + kc * 32 + quad * 8];
            half8 ain = -ai;
            #pragma unroll
            for (int j = 0; j < 3; ++j) {
                int o = wc * 48 + j * 16 + lr;
                half8 br = *(const half8*)&w1r[o * 96 + kc * 32 + quad * 8];
                half8 bi = *(const half8*)&w1i[o * 96 + kc * 32 + quad * 8];
                sr[j] = __builtin_amdgcn_mfma_f32_16x16x32_f16(ar,  br, sr[j], 0, 0, 0);
                sr[j] = __builtin_amdgcn_mfma_f32_16x16x32_f16(ain, bi, sr[j], 0, 0, 0);
                si[j] = __builtin_amdgcn_mfma_f32_16x16x32_f16(ai,  br, si[j], 0, 0, 0);
                si[j] = __builtin_amdgcn_mfma_f32_16x16x32_f16(ar,  bi, si[j], 0, 0, 0);
            }
        }
        #pragma unroll
        for (int j = 0; j < 3; ++j) {
            int o = wc * 48 + j * 16 + lr;
            float br = b1r[n * 96 + o], bi = b1i[n * 96 + o];
            #pragma unroll
            for (int r = 0; r < 4; ++r) {
                int kh = wr * 16 + quad * 4 + r;
                Sr[kh * 104 + o] = (_Float16)gelu_f(sr[j][r] + br);
                Si[kh * 104 + o] = (_Float16)gelu_f(si[j][r] + bi);
            }
        }
    }
    __syncthreads();

    // ---- stage C: T[kh][o] = shrink( S @ W2 + b2 ) complex -> store transposed T2T[o][kh] (alias XT)
    {
        float4v tr[3], ti[3];
        #pragma unroll
        for (int j = 0; j < 3; ++j) { float4v z = {0,0,0,0}; tr[j] = z; ti[j] = z; }
        #pragma unroll
        for (int kc = 0; kc < 3; ++kc) {
            half8 ar = *(const half8*)&Sr[(wr * 16 + lr) * 104 + kc * 32 + quad * 8];
            half8 ai = *(const half8*)&Si[(wr * 16 + lr) * 104 + kc * 32 + quad * 8];
            half8 ain = -ai;
            #pragma unroll
            for (int j = 0; j < 3; ++j) {
                int o = wc * 48 + j * 16 + lr;
                half8 br = *(const half8*)&w2r[o * 96 + kc * 32 + quad * 8];
                half8 bi = *(const half8*)&w2i[o * 96 + kc * 32 + quad * 8];
                tr[j] = __builtin_amdgcn_mfma_f32_16x16x32_f16(ar,  br, tr[j], 0, 0, 0);
                tr[j] = __builtin_amdgcn_mfma_f32_16x16x32_f16(ain, bi, tr[j], 0, 0, 0);
                ti[j] = __builtin_amdgcn_mfma_f32_16x16x32_f16(ai,  br, ti[j], 0, 0, 0);
                ti[j] = __builtin_amdgcn_mfma_f32_16x16x32_f16(ar,  bi, ti[j], 0, 0, 0);
            }
        }
        #pragma unroll
        for (int j = 0; j < 3; ++j) {
            int o = wc * 48 + j * 16 + lr;
            float br = b2r[n * 96 + o], bi = b2i[n * 96 + o];
            #pragma unroll
            for (int r = 0; r < 4; ++r) {
                int kh = wr * 16 + quad * 4 + r;
                XTr[o * 40 + kh] = (_Float16)shrink_f(tr[j][r] + br);
                XTi[o * 40 + kh] = (_Float16)shrink_f(ti[j][r] + bi);
            }
        }
    }
    __syncthreads();

    // ---- stage D: Y[h][c] = IDFT_h(T2); Yr = cos*Tr - sin*Ti ; Yi = cos*Ti + sin*Tr
    {
        float4v yr[3], yi[3];
        #pragma unroll
        for (int j = 0; j < 3; ++j) { float4v z = {0,0,0,0}; yr[j] = z; yi[j] = z; }
        #pragma unroll
        for (int j = 0; j < 3; ++j) {
            int c = wc * 48 + j * 16 + lr;
            half8 t2r = *(const half8*)&XTr[c * 40 + quad * 8];
            half8 t2i = *(const half8*)&XTi[c * 40 + quad * 8];
            yr[j] = __builtin_amdgcn_mfma_f32_16x16x32_f16(eC,  t2r, yr[j], 0, 0, 0);
            yr[j] = __builtin_amdgcn_mfma_f32_16x16x32_f16(eSn, t2i, yr[j], 0, 0, 0);
            yi[j] = __builtin_amdgcn_mfma_f32_16x16x32_f16(eC,  t2i, yi[j], 0, 0, 0);
            yi[j] = __builtin_amdgcn_mfma_f32_16x16x32_f16(eS,  t2r, yi[j], 0, 0, 0);
        }
        #pragma unroll
        for (int j = 0; j < 3; ++j) {
            int c = wc * 48 + j * 16 + lr;
            #pragma unroll
            for (int r = 0; r < 4; ++r) {
                int h = wr * 16 + quad * 4 + r;
                size_t g = base0 + (size_t)h * 13056 + c;
                Yr[g] = (_Float16)yr[j][r];
                Yi[g] = (_Float16)yi[j][r];
            }
        }
    }
}

// ---------------- f32 -> f16 elementwise (vectorized x4) ----------------
__global__ __launch_bounds__(256) void cvt_f16(const float* __restrict__ in,
        _Float16* __restrict__ out)
{
    int i = blockIdx.x * 256 + threadIdx.x;
    float4 v = ((const float4*)in)[i];
    half4v o;
    o.x = (_Float16)v.x; o.y = (_Float16)v.y; o.z = (_Float16)v.z; o.w = (_Float16)v.w;
    ((half4v*)out)[i] = o;
}

// ---------------- f32 [K][N] -> f16 [N][K] transpose ----------------
__global__ __launch_bounds__(256) void cvt_transpose(const float* __restrict__ in,
        _Float16* __restrict__ out, int K, int N)
{
    __shared__ float tile[32][33];
    int kb = blockIdx.x * 32, nb = blockIdx.y * 32;
    int tx = threadIdx.x & 31, ty = threadIdx.x >> 5;   // ty 0..7
    #pragma unroll
    for (int r = 0; r < 32; r += 8)
        tile[ty + r][tx] = in[(size_t)(kb + ty + r) * N + nb + tx];
    __syncthreads();
    #pragma unroll
    for (int r = 0; r < 32; r += 8)
        out[(size_t)(nb + ty + r) * K + kb + tx] = (_Float16)tile[tx][ty + r];
}

// ---------------- fp16 MFMA GEMM, double-buffered LDS ----------------
// C = act(A[M,K] @ Bt[N,K]^T + bias [+pos]); BM=128, BK=32, 256 thr = 4 waves 2x2.
// XCD-aware swizzle. OUT_MODE: 0 = f32, 1 = f16, 2 = dual, 3 = f32 pixel-shuffle scatter.
template<int BN, int OUT_MODE, int ACT>
__global__ __launch_bounds__(256) void gemm_h(const _Float16* __restrict__ A,
        const _Float16* __restrict__ Bt, const float* __restrict__ bias,
        const float* __restrict__ pos, float* __restrict__ C32,
        _Float16* __restrict__ C16, int M, int N, int K, int f_idx)
{
    constexpr int WN  = BN / 2;
    constexpr int FN  = WN / 16;
    constexpr int NBJ = BN / 64;
    __shared__ _Float16 Al[2][128 * 32];
    __shared__ _Float16 Bl[2][BN * 32];

    const int tid  = threadIdx.x;
    const int wave = tid >> 6;
    const int lane = tid & 63;
    const int wr   = wave >> 1;
    const int wc   = wave & 1;
    const int lr   = lane & 15;
    const int quad = lane >> 4;

    // XCD swizzle (dispatch round-robins linear id over 8 XCDs)
    const int gx = gridDim.x, nb = gx * gridDim.y;
    int bx = blockIdx.x, by = blockIdx.y;
    if (!(nb & 7)) {
        int id  = by * gx + bx;
        int id2 = (id & 7) * (nb >> 3) + (id >> 3);
        by = id2 / gx; bx = id2 % gx;
    }
    const int row0 = by * 128;
    const int col0 = bx * BN;

    const int srow = lane >> 2;
    const int skof = (lane & 3) * 8;

    auto stage = [&](int b, int k0) {
        #pragma unroll
        for (int j = 0; j < 2; ++j)
            async16(A + (size_t)(row0 + j * 64 + wave * 16 + srow) * K + k0 + skof,
                    &Al[b][(j * 64 + wave * 16) * 32]);
        #pragma unroll
        for (int j = 0; j < NBJ; ++j)
            async16(Bt + (size_t)(col0 + j * 64 + wave * 16 + srow) * K + k0 + skof,
                    &Bl[b][(j * 64 + wave * 16) * 32]);
    };

    float4v acc[4][FN];
    #pragma unroll
    for (int i = 0; i < 4; ++i)
        #pragma unroll
        for (int j = 0; j < FN; ++j) {
            float4v z = {0.f, 0.f, 0.f, 0.f};
            acc[i][j] = z;
        }

    const int KT = K >> 5;
    stage(0, 0);
    for (int kt = 0; kt < KT; ++kt) {
        __syncthreads();
        if (kt + 1 < KT) stage((kt + 1) & 1, (kt + 1) << 5);
        const int cb = kt & 1;
        half8 af[4], bf[FN];
        #pragma unroll
        for (int i = 0; i < 4; ++i)
            af[i] = *(const half8*)&Al[cb][(wr * 64 + i * 16 + lr) * 32 + quad * 8];
        #pragma unroll
        for (int j = 0; j < FN; ++j)
            bf[j] = *(const half8*)&Bl[cb][(wc * WN + j * 16 + lr) * 32 + quad * 8];
        #pragma unroll
        for (int i = 0; i < 4; ++i)
            #pragma unroll
            for (int j = 0; j < FN; ++j)
                acc[i][j] = __builtin_amdgcn_mfma_f32_16x16x32_f16(af[i], bf[j], acc[i][j], 0, 0, 0);
    }

    #pragma unroll
    for (int j = 0; j < FN; ++j) {
        int col = col0 + wc * WN + j * 16 + lr;
        float bj = bias[col];
        #pragma unroll
        for (int i = 0; i < 4; ++i) {
            int row = row0 + wr * 64 + i * 16 + quad * 4;
            #pragma unroll
            for (int r = 0; r < 4; ++r) {
                float v = acc[i][j][r] + bj;
                if (pos) v += pos[(size_t)((row + r) & 1023) * N + col];
                if (ACT) v = gelu_f(v);
                if (OUT_MODE == 3) {
                    int rowv = row + r;
                    int bq = rowv >> 10, hp = (rowv >> 5) & 31, wp = rowv & 31;
                    int p = col >> 3, q = col & 7;
                    C32[(((size_t)(bq * 256 + hp * 8 + p)) * 256 + wp * 8 + q) * 4 + f_idx] = v;
                } else {
                    size_t gi = (size_t)(row + r) * N + col;
                    if (OUT_MODE == 0 || OUT_MODE == 2) C32[gi] = v;
                    if (OUT_MODE == 1 || OUT_MODE == 2) C16[gi] = (_Float16)v;
                }
            }
        }
    }
}

// ---------------- launch ----------------
extern "C" void kernel_launch(void* const* d_in, const int* in_sizes, int n_in,
                              void* d_out, int out_size, void* d_ws, size_t ws_size,
                              hipStream_t stream) {
    const float* x        = (const float*)d_in[0];
    const float* grd      = (const float*)d_in[1];
    const float* conv_w   = (const float*)d_in[2];
    const float* conv_b   = (const float*)d_in[3];
    const float* pos_emb  = (const float*)d_in[4];
    const float* w1       = (const float*)d_in[5];
    const float* b1       = (const float*)d_in[6];
    const float* w2       = (const float*)d_in[7];
    const float* b2       = (const float*)d_in[8];
    const float* fc1_w    = (const float*)d_in[9];
    const float* fc1_b    = (const float*)d_in[10];
    const float* fc2_w    = (const float*)d_in[11];
    const float* fc2_b    = (const float*)d_in[12];
    const float* head_w1  = (const float*)d_in[13];
    const float* head_b1  = (const float*)d_in[14];
    const float* head_w2  = (const float*)d_in[15];
    const float* head_b2  = (const float*)d_in[16];
    float* out = (float*)d_out;
    float* ws  = (float*)d_ws;

    // ---- workspace layout, ALL sizes in float units; total 21,970,944 f = 87.9 MB ----
    float* pf = ws;
    float* t        = pf;              pf += 3145728;   // 4096x768 fp32
    _Float16* t_h     = (_Float16*)pf; pf += 1572864;   // 4096x768 f16
    _Float16* Wsp     = (_Float16*)pf; pf += 589824;    // 128x9216 f16 spectral weights
    _Float16* h1t     = (_Float16*)pf; pf += 589824;    // [1536][768] f16
    _Float16* h2t     = (_Float16*)pf; pf += 49152;     // [64][1536] f16
    _Float16* convw_h = (_Float16*)pf; pf += 294912;    // 768x768 f16 (prepass only)
    // ALIAS region: hid_h (4096x3072 f16 = 6,291,456 f) over 2 spectral f16 pairs
    // (4 x 835,584 f = 3,342,336 f). Disjoint live ranges.
    float* alias    = pf;              pf += 6291456;
    _Float16* hid_h = (_Float16*)alias;
    _Float16* xa_r  = (_Float16*)(alias);
    _Float16* xa_i  = (_Float16*)(alias + 835584);
    _Float16* xb_r  = (_Float16*)(alias + 1671168);
    _Float16* xb_i  = (_Float16*)(alias + 2506752);
    _Float16* WtAll = (_Float16*)pf;   pf += 9437184;   // 8 x [N][K] fc weights f16
    _Float16* A_h   = t_h;                              // prepass-only alias

    // ---- prepass: weight prep + patch embed (MFMA) ----
    prep_specw<<<dim3(128), 256, 0, stream>>>(w1, w2, Wsp);
    cvt_f16<<<dim3(576), 256, 0, stream>>>(conv_w, convw_h);
    cvt_transpose<<<dim3(24, 48), 256, 0, stream>>>(head_w1, h1t, 768, 1536);
    cvt_transpose<<<dim3(48, 2), 256, 0, stream>>>(head_w2, h2t, 1536, 64);
    for (int d = 0; d < 4; ++d) {
        cvt_transpose<<<dim3(24, 96), 256, 0, stream>>>(
            fc1_w + (size_t)d * 2359296, WtAll + (size_t)(2 * d) * 2359296, 768, 3072);
        cvt_transpose<<<dim3(96, 24), 256, 0, stream>>>(
            fc2_w + (size_t)d * 2359296, WtAll + (size_t)(2 * d + 1) * 2359296, 3072, 768);
    }
    gather_patch<<<dim3(12288), 256, 0, stream>>>(x, grd, A_h);
    gemm_h<128, 0, 0><<<dim3(6, 32), 256, 0, stream>>>(
        A_h, convw_h, conv_b, pos_emb, t, nullptr, 4096, 768, 768, 0);

    for (int f = 0; f < 4; ++f) {
        for (int d = 0; d < 4; ++d) {
            // rfft2 W-pass (ortho, 1/32 folded), f16 out
            dft_fwd_w<<<dim3(128, 3), 256, 0, stream>>>(t, xa_r, xa_i);
            // fused H-DFT + complex MLP + H-IDFT
            spec_fused<<<dim3(68, 8), 256, 0, stream>>>(
                xa_r, xa_i,
                Wsp + (size_t)(d * 4 + 0) * 73728, Wsp + (size_t)(d * 4 + 1) * 73728,
                Wsp + (size_t)(d * 4 + 2) * 73728, Wsp + (size_t)(d * 4 + 3) * 73728,
                b1 + d * 1536, b1 + d * 1536 + 768,
                b2 + d * 1536, b2 + d * 1536 + 768,
                xb_r, xb_i);
            // irfft2 W-pass + residual (dual fp32/f16 write)
            dft_inv_w<<<dim3(128, 3), 256, 0, stream>>>(xb_r, xb_i, t, t_h);
            // channel MLP 768 -> 3072 -> 768 via fp16 MFMA (hid_h aliases dead spectral bufs)
            gemm_h<128, 1, 1><<<dim3(24, 32), 256, 0, stream>>>(
                t_h, WtAll + (size_t)(2 * d) * 2359296, fc1_b + d * 3072,
                nullptr, nullptr, hid_h, 4096, 3072, 768, 0);
            gemm_h<64, 2, 0><<<dim3(12, 32), 256, 0, stream>>>(
                hid_h, WtAll + (size_t)(2 * d + 1) * 2359296, fc2_b + d * 768,
                nullptr, t, t_h, 4096, 768, 3072, 0);
        }
        // head on current state (t_h mirrors t); head2 scatters straight into out
        gemm_h<128, 1, 1><<<dim3(12, 32), 256, 0, stream>>>(
            t_h, h1t, head_b1, nullptr, nullptr, hid_h, 4096, 1536, 768, 0);
        gemm_h<64, 3, 0><<<dim3(1, 32), 256, 0, stream>>>(
            hid_h, h2t, head_b2, nullptr, out, nullptr, 4096, 64, 1536, f);
    }
}

// Round 8
// 2763.933 us; speedup vs baseline: 1.6890x; 1.1139x over previous
//
#include <hip/hip_runtime.h>
#include <hip/hip_bf16.h>
#include <math.h>

// ---------------- static config ----------------
// B=4, H=W=256, TIN=10, F=4, P=8, CIN=12, E=768, NB=8, BS=96,
// HP=WP=32, MID=3072, DEPTH=4, LAM=0.01, WF=17, TOK=4096, POS=B*32*17=2176
// Spectral layout: X[((b*17+kw)*32 + h)*768 + c]   (h-rows contiguous per kw)

typedef __attribute__((ext_vector_type(8))) _Float16 half8;
typedef __attribute__((ext_vector_type(4))) _Float16 half4v;
typedef __attribute__((ext_vector_type(4))) float float4v;

__device__ __forceinline__ float gelu_f(float v) {
    return 0.5f * v * (1.0f + erff(v * 0.70710678118654752f));
}
__device__ __forceinline__ float shrink_f(float v) {
    return (v > 0.01f) ? (v - 0.01f) : ((v < -0.01f) ? (v + 0.01f) : 0.0f);
}

#define STEP32 0.19634954084936207f  // 2*pi/32

// async 16B global->LDS (lds dest wave-uniform; HW adds lane*16)
__device__ __forceinline__ void async16(const void* g, void* l) {
    __builtin_amdgcn_global_load_lds(
        (const __attribute__((address_space(1))) unsigned int*)g,
        (__attribute__((address_space(3))) unsigned int*)l, 16, 0, 0);
}

// ---------------- gather patches into A_h [4096][768] f16 ----------------
__global__ __launch_bounds__(256) void gather_patch(const float* __restrict__ x,
        const float* __restrict__ grd, _Float16* __restrict__ A)
{
    int idx = blockIdx.x * 256 + threadIdx.x;
    int j   = idx % 768;
    int tok = idx / 768;
    int c = j >> 6, p = (j >> 3) & 7, q = j & 7;
    int wp = tok & 31, hp = (tok >> 5) & 31, b = tok >> 10;
    int hh = hp * 8 + p, ww = wp * 8 + q;
    float v;
    if (c < 10) v = x[((b * 256 + hh) * 256 + ww) * 10 + c];
    else        v = grd[((b * 256 + hh) * 256 + ww) * 2 + (c - 10)];
    A[idx] = (_Float16)v;
}

// ---------------- forward DFT along W (real fp32 -> 17 complex f16), scale 1/32 ----------------
// prepass + fallback path. out layout [b,kw,h,c]
__global__ __launch_bounds__(256) void dft_fwd_w(const float* __restrict__ t,
        _Float16* __restrict__ Xr, _Float16* __restrict__ Xi)
{
    __shared__ float2 lut[32];
    int bh = blockIdx.x;            // b*32 + h
    int tid = threadIdx.x;
    if (tid < 32) { float a = tid * STEP32; lut[tid] = make_float2(cosf(a), sinf(a)); }
    __syncthreads();
    int b = bh >> 5, h = bh & 31;
    int c = blockIdx.y * 256 + tid;
    float v[32];
    #pragma unroll
    for (int w = 0; w < 32; ++w) v[w] = t[(bh * 32 + w) * 768 + c];
    for (int kw = 0; kw <= 16; ++kw) {
        float ar = 0.f, ai = 0.f;
        #pragma unroll
        for (int w = 0; w < 32; ++w) {
            float2 cs = lut[(kw * w) & 31];
            ar += v[w] * cs.x;
            ai -= v[w] * cs.y;
        }
        size_t g = ((size_t)(b * 17 + kw) * 32 + h) * 768 + c;
        Xr[g] = (_Float16)(ar * 0.03125f);
        Xi[g] = (_Float16)(ai * 0.03125f);
    }
}

// ---------------- inverse DFT along W (f16 in, [b,kw,h,c]) + residual; dual write ----------------
__global__ __launch_bounds__(256) void dft_inv_w(const _Float16* __restrict__ Yr,
        const _Float16* __restrict__ Yi,
        float* __restrict__ t, _Float16* __restrict__ t_h)
{
    __shared__ float2 lut[32];
    int bh = blockIdx.x;
    int tid = threadIdx.x;
    if (tid < 32) { float a = tid * STEP32; lut[tid] = make_float2(cosf(a), sinf(a)); }
    __syncthreads();
    int b = bh >> 5, h = bh & 31;
    int c = blockIdx.y * 256 + tid;
    float yr[17], yi[16];
    #pragma unroll
    for (int k = 0; k <= 16; ++k) yr[k] = (float)Yr[((size_t)(b * 17 + k) * 32 + h) * 768 + c];
    #pragma unroll
    for (int k = 1; k <= 15; ++k) yi[k] = (float)Yi[((size_t)(b * 17 + k) * 32 + h) * 768 + c];
    for (int w = 0; w < 32; ++w) {
        float val = yr[0] + ((w & 1) ? -yr[16] : yr[16]);
        #pragma unroll
        for (int k = 1; k <= 15; ++k) {
            float2 cs = lut[(k * w) & 31];
            val += 2.f * (yr[k] * cs.x - yi[k] * cs.y);
        }
        int gi = (bh * 32 + w) * 768 + c;
        float r = val * 0.03125f + t[gi];
        t[gi] = r;
        t_h[gi] = (_Float16)r;
    }
}

// ---------------- spectral weight prep: [i][o] fp32 -> [o][i] f16, 128 matrices ----------------
__global__ __launch_bounds__(256) void prep_specw(const float* __restrict__ w1,
        const float* __restrict__ w2, _Float16* __restrict__ out)
{
    __shared__ float tile[96][97];
    int mid = blockIdx.x;
    int n  = mid & 7;
    int ri = (mid >> 3) & 1;
    int l  = (mid >> 4) & 1;
    int d  = mid >> 5;
    const float* src = (l ? w2 : w1) + ((size_t)(d * 2 + ri) * 8 + n) * 9216;
    for (int idx = threadIdx.x; idx < 9216; idx += 256)
        tile[idx / 96][idx % 96] = src[idx];
    __syncthreads();
    _Float16* dst = out + (size_t)mid * 9216;
    for (int idx = threadIdx.x; idx < 9216; idx += 256)
        dst[idx] = (_Float16)tile[idx % 96][idx / 96];   // dst[o][i] = src[i][o]
}

// ---------------- fused spectral: H-DFT -> spec1(gelu) -> spec2(shrink) -> H-IDFT ----------------
// IN-PLACE on X ([b,kw,h,c] layout). grid (68 = b*17+kw, 8 = n); 256 thr = 4 waves.
__global__ __launch_bounds__(256) void spec_fused(
        _Float16* __restrict__ Xr, _Float16* __restrict__ Xi,
        const _Float16* __restrict__ W1r, const _Float16* __restrict__ W1i,
        const _Float16* __restrict__ W2r, const _Float16* __restrict__ W2i,
        const float* __restrict__ b1r, const float* __restrict__ b1i,
        const float* __restrict__ b2r, const float* __restrict__ b2i)
{
    __shared__ alignas(16) _Float16 Ec[1024], Es[1024];       // [m][k] twiddle 32x32
    __shared__ alignas(16) _Float16 XTr[3840], XTi[3840];     // [c][h] pad40; stage C: [o][kh]
    __shared__ alignas(16) _Float16 Zr[3328], Zi[3328];       // [kh][c] pad104; stage D out [h][c]
    __shared__ alignas(16) _Float16 Sr[3328], Si[3328];       // [kh][o] pad104

    const int bk = blockIdx.x;       // b*17 + kw
    const int n  = blockIdx.y;
    const int tid = threadIdx.x;
    const int wave = tid >> 6, lane = tid & 63;
    const int wr = wave >> 1, wc = wave & 1;
    const int lr = lane & 15, quad = lane >> 4;
    const size_t base = (size_t)bk * 24576 + n * 96;    // + h*768 + c

    for (int i = tid; i < 1024; i += 256) {
        int kh = i >> 5, h = i & 31;
        float a = ((kh * h) & 31) * STEP32;
        Ec[i] = (_Float16)cosf(a);
        Es[i] = (_Float16)sinf(a);
    }
    // vector load -> LDS transpose [c][h]
    for (int i = tid; i < 384; i += 256) {
        int h = i / 12, cc = (i % 12) * 8;
        half8 vr = *(const half8*)(Xr + base + (size_t)h * 768 + cc);
        half8 vi = *(const half8*)(Xi + base + (size_t)h * 768 + cc);
        #pragma unroll
        for (int e = 0; e < 8; ++e) {
            XTr[(cc + e) * 40 + h] = vr[e];
            XTi[(cc + e) * 40 + h] = vi[e];
        }
    }
    __syncthreads();

    const _Float16* w1r = W1r + (size_t)n * 9216;
    const _Float16* w1i = W1i + (size_t)n * 9216;
    const _Float16* w2r = W2r + (size_t)n * 9216;
    const _Float16* w2i = W2i + (size_t)n * 9216;

    half8 eC = *(const half8*)&Ec[(wr * 16 + lr) * 32 + quad * 8];
    half8 eS = *(const half8*)&Es[(wr * 16 + lr) * 32 + quad * 8];
    half8 eSn = -eS;

    // stage A: Z[kh][c] = DFT_h(X)
    {
        float4v zr[3], zi[3];
        #pragma unroll
        for (int j = 0; j < 3; ++j) { float4v z = {0,0,0,0}; zr[j] = z; zi[j] = z; }
        #pragma unroll
        for (int j = 0; j < 3; ++j) {
            int c = wc * 48 + j * 16 + lr;
            half8 xr = *(const half8*)&XTr[c * 40 + quad * 8];
            half8 xi = *(const half8*)&XTi[c * 40 + quad * 8];
            zr[j] = __builtin_amdgcn_mfma_f32_16x16x32_f16(eC,  xr, zr[j], 0, 0, 0);
            zr[j] = __builtin_amdgcn_mfma_f32_16x16x32_f16(eS,  xi, zr[j], 0, 0, 0);
            zi[j] = __builtin_amdgcn_mfma_f32_16x16x32_f16(eC,  xi, zi[j], 0, 0, 0);
            zi[j] = __builtin_amdgcn_mfma_f32_16x16x32_f16(eSn, xr, zi[j], 0, 0, 0);
        }
        #pragma unroll
        for (int j = 0; j < 3; ++j) {
            int c = wc * 48 + j * 16 + lr;
            #pragma unroll
            for (int r = 0; r < 4; ++r) {
                int kh = wr * 16 + quad * 4 + r;
                Zr[kh * 104 + c] = (_Float16)zr[j][r];
                Zi[kh * 104 + c] = (_Float16)zi[j][r];
            }
        }
    }
    __syncthreads();

    // stage B: S = gelu(Z @ W1 + b1)
    {
        float4v sr[3], si[3];
        #pragma unroll
        for (int j = 0; j < 3; ++j) { float4v z = {0,0,0,0}; sr[j] = z; si[j] = z; }
        #pragma unroll
        for (int kc = 0; kc < 3; ++kc) {
            half8 ar = *(const half8*)&Zr[(wr * 16 + lr) * 104 + kc * 32 + quad * 8];
            half8 ai = *(const half8*)&Zi[(wr * 16 + lr) * 104 + kc * 32 + quad * 8];
            half8 ain = -ai;
            #pragma unroll
            for (int j = 0; j < 3; ++j) {
                int o = wc * 48 + j * 16 + lr;
                half8 br = *(const half8*)&w1r[o * 96 + kc * 32 + quad * 8];
                half8 bi = *(const half8*)&w1i[o * 96 + kc * 32 + quad * 8];
                sr[j] = __builtin_amdgcn_mfma_f32_16x16x32_f16(ar,  br, sr[j], 0, 0, 0);
                sr[j] = __builtin_amdgcn_mfma_f32_16x16x32_f16(ain, bi, sr[j], 0, 0, 0);
                si[j] = __builtin_amdgcn_mfma_f32_16x16x32_f16(ai,  br, si[j], 0, 0, 0);
                si[j] = __builtin_amdgcn_mfma_f32_16x16x32_f16(ar,  bi, si[j], 0, 0, 0);
            }
        }
        #pragma unroll
        for (int j = 0; j < 3; ++j) {
            int o = wc * 48 + j * 16 + lr;
            float br = b1r[n * 96 + o], bi = b1i[n * 96 + o];
            #pragma unroll
            for (int r = 0; r < 4; ++r) {
                int kh = wr * 16 + quad * 4 + r;
                Sr[kh * 104 + o] = (_Float16)gelu_f(sr[j][r] + br);
                Si[kh * 104 + o] = (_Float16)gelu_f(si[j][r] + bi);
            }
        }
    }
    __syncthreads();

    // stage C: T = shrink(S @ W2 + b2) -> transposed T2T[o][kh] (alias XT)
    {
        float4v tr[3], ti[3];
        #pragma unroll
        for (int j = 0; j < 3; ++j) { float4v z = {0,0,0,0}; tr[j] = z; ti[j] = z; }
        #pragma unroll
        for (int kc = 0; kc < 3; ++kc) {
            half8 ar = *(const half8*)&Sr[(wr * 16 + lr) * 104 + kc * 32 + quad * 8];
            half8 ai = *(const half8*)&Si[(wr * 16 + lr) * 104 + kc * 32 + quad * 8];
            half8 ain = -ai;
            #pragma unroll
            for (int j = 0; j < 3; ++j) {
                int o = wc * 48 + j * 16 + lr;
                half8 br = *(const half8*)&w2r[o * 96 + kc * 32 + quad * 8];
                half8 bi = *(const half8*)&w2i[o * 96 + kc * 32 + quad * 8];
                tr[j] = __builtin_amdgcn_mfma_f32_16x16x32_f16(ar,  br, tr[j], 0, 0, 0);
                tr[j] = __builtin_amdgcn_mfma_f32_16x16x32_f16(ain, bi, tr[j], 0, 0, 0);
                ti[j] = __builtin_amdgcn_mfma_f32_16x16x32_f16(ai,  br, ti[j], 0, 0, 0);
                ti[j] = __builtin_amdgcn_mfma_f32_16x16x32_f16(ar,  bi, ti[j], 0, 0, 0);
            }
        }
        #pragma unroll
        for (int j = 0; j < 3; ++j) {
            int o = wc * 48 + j * 16 + lr;
            float br = b2r[n * 96 + o], bi = b2i[n * 96 + o];
            #pragma unroll
            for (int r = 0; r < 4; ++r) {
                int kh = wr * 16 + quad * 4 + r;
                XTr[o * 40 + kh] = (_Float16)shrink_f(tr[j][r] + br);
                XTi[o * 40 + kh] = (_Float16)shrink_f(ti[j][r] + bi);
            }
        }
    }
    __syncthreads();

    // stage D: Y[h][c] = IDFT_h(T2) -> Zr/Zi as [h][c] pad104
    {
        float4v yr[3], yi[3];
        #pragma unroll
        for (int j = 0; j < 3; ++j) { float4v z = {0,0,0,0}; yr[j] = z; yi[j] = z; }
        #pragma unroll
        for (int j = 0; j < 3; ++j) {
            int c = wc * 48 + j * 16 + lr;
            half8 t2r = *(const half8*)&XTr[c * 40 + quad * 8];
            half8 t2i = *(const half8*)&XTi[c * 40 + quad * 8];
            yr[j] = __builtin_amdgcn_mfma_f32_16x16x32_f16(eC,  t2r, yr[j], 0, 0, 0);
            yr[j] = __builtin_amdgcn_mfma_f32_16x16x32_f16(eSn, t2i, yr[j], 0, 0, 0);
            yi[j] = __builtin_amdgcn_mfma_f32_16x16x32_f16(eC,  t2i, yi[j], 0, 0, 0);
            yi[j] = __builtin_amdgcn_mfma_f32_16x16x32_f16(eS,  t2r, yi[j], 0, 0, 0);
        }
        #pragma unroll
        for (int j = 0; j < 3; ++j) {
            int c = wc * 48 + j * 16 + lr;
            #pragma unroll
            for (int r = 0; r < 4; ++r) {
                int h = wr * 16 + quad * 4 + r;
                Zr[h * 104 + c] = (_Float16)yr[j][r];
                Zi[h * 104 + c] = (_Float16)yi[j][r];
            }
        }
    }
    __syncthreads();

    // vector store back (in-place)
    for (int i = tid; i < 384; i += 256) {
        int h = i / 12, cc = (i % 12) * 8;
        half8 vr = *(const half8*)&Zr[h * 104 + cc];
        half8 vi = *(const half8*)&Zi[h * 104 + cc];
        *(half8*)(Xr + base + (size_t)h * 768 + cc) = vr;
        *(half8*)(Xi + base + (size_t)h * 768 + cc) = vi;
    }
}

// ---------------- f32 -> f16 elementwise (vectorized x4) ----------------
__global__ __launch_bounds__(256) void cvt_f16(const float* __restrict__ in,
        _Float16* __restrict__ out)
{
    int i = blockIdx.x * 256 + threadIdx.x;
    float4 v = ((const float4*)in)[i];
    half4v o;
    o.x = (_Float16)v.x; o.y = (_Float16)v.y; o.z = (_Float16)v.z; o.w = (_Float16)v.w;
    ((half4v*)out)[i] = o;
}

// ---------------- f32 [K][N] -> f16 [N][K] transpose ----------------
__global__ __launch_bounds__(256) void cvt_transpose(const float* __restrict__ in,
        _Float16* __restrict__ out, int K, int N)
{
    __shared__ float tile[32][33];
    int kb = blockIdx.x * 32, nb = blockIdx.y * 32;
    int tx = threadIdx.x & 31, ty = threadIdx.x >> 5;
    #pragma unroll
    for (int r = 0; r < 32; r += 8)
        tile[ty + r][tx] = in[(size_t)(kb + ty + r) * N + nb + tx];
    __syncthreads();
    #pragma unroll
    for (int r = 0; r < 32; r += 8)
        out[(size_t)(nb + ty + r) * K + kb + tx] = (_Float16)tile[tx][ty + r];
}

// ---------------- fp16 MFMA GEMM, double-buffered LDS ----------------
// OUT_MODE: 0 = f32, 1 = f16, 2 = dual, 3 = f32 pixel-shuffle scatter,
//           4 = dual + fused forward W-DFT epilogue (fc2: writes XR/XI [b,kw,h,c])
template<int BN, int OUT_MODE, int ACT>
__global__ __launch_bounds__(256) void gemm_h(const _Float16* __restrict__ A,
        const _Float16* __restrict__ Bt, const float* __restrict__ bias,
        const float* __restrict__ pos, float* __restrict__ C32,
        _Float16* __restrict__ C16, _Float16* __restrict__ XR,
        _Float16* __restrict__ XI, int M, int N, int K, int f_idx)
{
    constexpr int WN  = BN / 2;
    constexpr int FN  = WN / 16;
    constexpr int NBJ = BN / 64;
    __shared__ _Float16 Al[2][128 * 32];
    __shared__ _Float16 Bl[2][BN * 32];

    const int tid  = threadIdx.x;
    const int wave = tid >> 6;
    const int lane = tid & 63;
    const int wr   = wave >> 1;
    const int wc   = wave & 1;
    const int lr   = lane & 15;
    const int quad = lane >> 4;

    const int gx = gridDim.x, nb = gx * gridDim.y;
    int bx = blockIdx.x, by = blockIdx.y;
    if (!(nb & 7)) {
        int id  = by * gx + bx;
        int id2 = (id & 7) * (nb >> 3) + (id >> 3);
        by = id2 / gx; bx = id2 % gx;
    }
    const int row0 = by * 128;
    const int col0 = bx * BN;

    const int srow = lane >> 2;
    const int skof = (lane & 3) * 8;

    auto stage = [&](int b, int k0) {
        #pragma unroll
        for (int j = 0; j < 2; ++j)
            async16(A + (size_t)(row0 + j * 64 + wave * 16 + srow) * K + k0 + skof,
                    &Al[b][(j * 64 + wave * 16) * 32]);
        #pragma unroll
        for (int j = 0; j < NBJ; ++j)
            async16(Bt + (size_t)(col0 + j * 64 + wave * 16 + srow) * K + k0 + skof,
                    &Bl[b][(j * 64 + wave * 16) * 32]);
    };

    float4v acc[4][FN];
    #pragma unroll
    for (int i = 0; i < 4; ++i)
        #pragma unroll
        for (int j = 0; j < FN; ++j) {
            float4v z = {0.f, 0.f, 0.f, 0.f};
            acc[i][j] = z;
        }

    const int KT = K >> 5;
    stage(0, 0);
    for (int kt = 0; kt < KT; ++kt) {
        __syncthreads();
        if (kt + 1 < KT) stage((kt + 1) & 1, (kt + 1) << 5);
        const int cb = kt & 1;
        half8 af[4], bf[FN];
        #pragma unroll
        for (int i = 0; i < 4; ++i)
            af[i] = *(const half8*)&Al[cb][(wr * 64 + i * 16 + lr) * 32 + quad * 8];
        #pragma unroll
        for (int j = 0; j < FN; ++j)
            bf[j] = *(const half8*)&Bl[cb][(wc * WN + j * 16 + lr) * 32 + quad * 8];
        #pragma unroll
        for (int i = 0; i < 4; ++i)
            #pragma unroll
            for (int j = 0; j < FN; ++j)
                acc[i][j] = __builtin_amdgcn_mfma_f32_16x16x32_f16(af[i], bf[j], acc[i][j], 0, 0, 0);
    }

    if constexpr (OUT_MODE == 4) {
        // fc2 epilogue: dual write + stage tile + fused forward W-DFT
        __shared__ alignas(16) _Float16 Tl[4 * 64 * 32];   // [h][c][w]
        __shared__ alignas(16) _Float16 ECl[1024], ESl[1024];
        for (int i = tid; i < 1024; i += 256) {
            int kw = i >> 5, w = i & 31;
            float a = ((kw * w) & 31) * STEP32;
            ECl[i] = (_Float16)(cosf(a) * 0.03125f);
            ESl[i] = (_Float16)(-sinf(a) * 0.03125f);
        }
        #pragma unroll
        for (int j = 0; j < FN; ++j) {
            int col = col0 + wc * WN + j * 16 + lr;
            float bj = bias[col];
            #pragma unroll
            for (int i = 0; i < 4; ++i) {
                int row = row0 + wr * 64 + i * 16 + quad * 4;
                #pragma unroll
                for (int r = 0; r < 4; ++r) {
                    float v = acc[i][j][r] + bj;
                    size_t gi = (size_t)(row + r) * N + col;
                    C32[gi] = v;
                    C16[gi] = (_Float16)v;
                    int lrow = row + r - row0;
                    Tl[(((lrow >> 5) * 64) + (col - col0)) * 32 + (lrow & 31)] = (_Float16)v;
                }
            }
        }
        __syncthreads();
        // per-wave h-row DFT: X[kw][c] = E @ T   (wave = local h)
        const int b  = row0 >> 10;
        const int hp = ((row0 >> 5) & 31) + wave;
        half8 eC0 = *(const half8*)&ECl[lr * 32 + quad * 8];
        half8 eC1 = *(const half8*)&ECl[(16 + lr) * 32 + quad * 8];
        half8 eS0 = *(const half8*)&ESl[lr * 32 + quad * 8];
        half8 eS1 = *(const half8*)&ESl[(16 + lr) * 32 + quad * 8];
        float4v xr[2][4], xi[2][4];
        #pragma unroll
        for (int m = 0; m < 2; ++m)
            #pragma unroll
            for (int nj = 0; nj < 4; ++nj) {
                float4v z = {0.f, 0.f, 0.f, 0.f};
                xr[m][nj] = z; xi[m][nj] = z;
            }
        #pragma unroll
        for (int nj = 0; nj < 4; ++nj) {
            half8 tb = *(const half8*)&Tl[((wave * 64) + nj * 16 + lr) * 32 + quad * 8];
            xr[0][nj] = __builtin_amdgcn_mfma_f32_16x16x32_f16(eC0, tb, xr[0][nj], 0, 0, 0);
            xr[1][nj] = __builtin_amdgcn_mfma_f32_16x16x32_f16(eC1, tb, xr[1][nj], 0, 0, 0);
            xi[0][nj] = __builtin_amdgcn_mfma_f32_16x16x32_f16(eS0, tb, xi[0][nj], 0, 0, 0);
            xi[1][nj] = __builtin_amdgcn_mfma_f32_16x16x32_f16(eS1, tb, xi[1][nj], 0, 0, 0);
        }
        #pragma unroll
        for (int m = 0; m < 2; ++m)
            #pragma unroll
            for (int r = 0; r < 4; ++r) {
                int kw = m * 16 + quad * 4 + r;
                if (kw < 17) {
                    #pragma unroll
                    for (int nj = 0; nj < 4; ++nj) {
                        int c = col0 + nj * 16 + lr;
                        size_t g = ((size_t)(b * 17 + kw) * 32 + hp) * 768 + c;
                        XR[g] = (_Float16)xr[m][nj][r];
                        XI[g] = (_Float16)xi[m][nj][r];
                    }
                }
            }
    } else {
        #pragma unroll
        for (int j = 0; j < FN; ++j) {
            int col = col0 + wc * WN + j * 16 + lr;
            float bj = bias[col];
            #pragma unroll
            for (int i = 0; i < 4; ++i) {
                int row = row0 + wr * 64 + i * 16 + quad * 4;
                #pragma unroll
                for (int r = 0; r < 4; ++r) {
                    float v = acc[i][j][r] + bj;
                    if (pos) v += pos[(size_t)((row + r) & 1023) * N + col];
                    if (ACT) v = gelu_f(v);
                    if (OUT_MODE == 3) {
                        int rowv = row + r;
                        int bq = rowv >> 10, hp = (rowv >> 5) & 31, wp = rowv & 31;
                        int p = col >> 3, q = col & 7;
                        C32[(((size_t)(bq * 256 + hp * 8 + p)) * 256 + wp * 8 + q) * 4 + f_idx] = v;
                    } else {
                        size_t gi = (size_t)(row + r) * N + col;
                        if (OUT_MODE == 0 || OUT_MODE == 2) C32[gi] = v;
                        if (OUT_MODE == 1 || OUT_MODE == 2) C16[gi] = (_Float16)v;
                    }
                }
            }
        }
    }
}

// ---------------- launch ----------------
extern "C" void kernel_launch(void* const* d_in, const int* in_sizes, int n_in,
                              void* d_out, int out_size, void* d_ws, size_t ws_size,
                              hipStream_t stream) {
    const float* x        = (const float*)d_in[0];
    const float* grd      = (const float*)d_in[1];
    const float* conv_w   = (const float*)d_in[2];
    const float* conv_b   = (const float*)d_in[3];
    const float* pos_emb  = (const float*)d_in[4];
    const float* w1       = (const float*)d_in[5];
    const float* b1       = (const float*)d_in[6];
    const float* w2       = (const float*)d_in[7];
    const float* b2       = (const float*)d_in[8];
    const float* fc1_w    = (const float*)d_in[9];
    const float* fc1_b    = (const float*)d_in[10];
    const float* fc2_w    = (const float*)d_in[11];
    const float* fc2_b    = (const float*)d_in[12];
    const float* head_w1  = (const float*)d_in[13];
    const float* head_b1  = (const float*)d_in[14];
    const float* head_w2  = (const float*)d_in[15];
    const float* head_b2  = (const float*)d_in[16];
    float* out = (float*)d_out;
    float* ws  = (float*)d_ws;

    // ---- workspace layout, sizes in float units ----
    float* pf = ws;
    float* t        = pf;              pf += 3145728;   // 4096x768 fp32
    _Float16* t_h     = (_Float16*)pf; pf += 1572864;   // 4096x768 f16
    _Float16* Wsp     = (_Float16*)pf; pf += 589824;    // 128x9216 f16 spectral weights
    _Float16* h1t     = (_Float16*)pf; pf += 589824;    // [1536][768] f16
    _Float16* h2t     = (_Float16*)pf; pf += 49152;     // [64][1536] f16
    _Float16* convw_h = (_Float16*)pf; pf += 294912;    // 768x768 f16 (prepass only)
    float* alias    = pf;              pf += 6291456;   // hid_h 4096x3072 f16
    _Float16* hid_h = (_Float16*)alias;
    _Float16* WtAll = (_Float16*)pf;   pf += 9437184;   // 8 x [N][K] fc weights f16
    // fallback xa inside alias (hid dead when xa live); full mode: dedicated xa after WtAll
    _Float16* xa_r_fb = (_Float16*)alias;
    _Float16* xa_i_fb = (_Float16*)(alias + 835584);
    _Float16* xa_r_fu = (_Float16*)pf;                  // +835,584 f
    _Float16* xa_i_fu = (_Float16*)(pf + 835584);       // +835,584 f
    size_t full_total = (size_t)(pf - ws) + 1671168;    // 23,642,112 f = 94.57 MB
    bool full = ws_size >= full_total * 4ull;
    _Float16* xa_r = full ? xa_r_fu : xa_r_fb;
    _Float16* xa_i = full ? xa_i_fu : xa_i_fb;
    _Float16* A_h  = t_h;                               // prepass-only alias

    // ---- prepass ----
    prep_specw<<<dim3(128), 256, 0, stream>>>(w1, w2, Wsp);
    cvt_f16<<<dim3(576), 256, 0, stream>>>(conv_w, convw_h);
    cvt_transpose<<<dim3(24, 48), 256, 0, stream>>>(head_w1, h1t, 768, 1536);
    cvt_transpose<<<dim3(48, 2), 256, 0, stream>>>(head_w2, h2t, 1536, 64);
    for (int d = 0; d < 4; ++d) {
        cvt_transpose<<<dim3(24, 96), 256, 0, stream>>>(
            fc1_w + (size_t)d * 2359296, WtAll + (size_t)(2 * d) * 2359296, 768, 3072);
        cvt_transpose<<<dim3(96, 24), 256, 0, stream>>>(
            fc2_w + (size_t)d * 2359296, WtAll + (size_t)(2 * d + 1) * 2359296, 3072, 768);
    }
    gather_patch<<<dim3(12288), 256, 0, stream>>>(x, grd, A_h);
    gemm_h<128, 0, 0><<<dim3(6, 32), 256, 0, stream>>>(
        A_h, convw_h, conv_b, pos_emb, t, nullptr, nullptr, nullptr, 4096, 768, 768, 0);
    dft_fwd_w<<<dim3(128, 3), 256, 0, stream>>>(t, xa_r, xa_i);

    for (int f = 0; f < 4; ++f) {
        for (int d = 0; d < 4; ++d) {
            // fused H-DFT + complex MLP + H-IDFT (in-place on xa)
            spec_fused<<<dim3(68, 8), 256, 0, stream>>>(
                xa_r, xa_i,
                Wsp + (size_t)(d * 4 + 0) * 73728, Wsp + (size_t)(d * 4 + 1) * 73728,
                Wsp + (size_t)(d * 4 + 2) * 73728, Wsp + (size_t)(d * 4 + 3) * 73728,
                b1 + d * 1536, b1 + d * 1536 + 768,
                b2 + d * 1536, b2 + d * 1536 + 768);
            // irfft2 W-pass + residual (dual fp32/f16 write)
            dft_inv_w<<<dim3(128, 3), 256, 0, stream>>>(xa_r, xa_i, t, t_h);
            // channel MLP
            gemm_h<128, 1, 1><<<dim3(24, 32), 256, 0, stream>>>(
                t_h, WtAll + (size_t)(2 * d) * 2359296, fc1_b + d * 3072,
                nullptr, nullptr, hid_h, nullptr, nullptr, 4096, 3072, 768, 0);
            if (full) {
                // fc2 + fused forward W-DFT (seeds xa for the next spectral block)
                gemm_h<64, 4, 0><<<dim3(12, 32), 256, 0, stream>>>(
                    hid_h, WtAll + (size_t)(2 * d + 1) * 2359296, fc2_b + d * 768,
                    nullptr, t, t_h, xa_r, xa_i, 4096, 768, 3072, 0);
            } else {
                gemm_h<64, 2, 0><<<dim3(12, 32), 256, 0, stream>>>(
                    hid_h, WtAll + (size_t)(2 * d + 1) * 2359296, fc2_b + d * 768,
                    nullptr, t, t_h, nullptr, nullptr, 4096, 768, 3072, 0);
                dft_fwd_w<<<dim3(128, 3), 256, 0, stream>>>(t, xa_r, xa_i);
            }
        }
        // head on current state (t_h from fc2)
        gemm_h<128, 1, 1><<<dim3(12, 32), 256, 0, stream>>>(
            t_h, h1t, head_b1, nullptr, nullptr, hid_h, nullptr, nullptr, 4096, 1536, 768, 0);
        gemm_h<64, 3, 0><<<dim3(1, 32), 256, 0, stream>>>(
            hid_h, h2t, head_b2, nullptr, out, nullptr, nullptr, nullptr, 4096, 64, 1536, f);
    }
}

// Round 9
// 2699.932 us; speedup vs baseline: 1.7290x; 1.0237x over previous
//
#include <hip/hip_runtime.h>
#include <hip/hip_bf16.h>
#include <math.h>

// ---------------- static config ----------------
// B=4, H=W=256, TIN=10, F=4, P=8, CIN=12, E=768, NB=8, BS=96,
// HP=WP=32, MID=3072, DEPTH=4, LAM=0.01, WF=17, TOK=4096, POS=B*32*17=2176
// Spectral layout: X[((b*17+kw)*32 + h)*768 + c]   (h-rows contiguous per kw)
// Residual state t lives in f16 only (t_h); fp32 copy dropped (R9).

typedef __attribute__((ext_vector_type(8))) _Float16 half8;
typedef __attribute__((ext_vector_type(4))) _Float16 half4v;
typedef __attribute__((ext_vector_type(4))) float float4v;

__device__ __forceinline__ float gelu_f(float v) {
    return 0.5f * v * (1.0f + erff(v * 0.70710678118654752f));
}
__device__ __forceinline__ float shrink_f(float v) {
    return (v > 0.01f) ? (v - 0.01f) : ((v < -0.01f) ? (v + 0.01f) : 0.0f);
}

#define STEP32 0.19634954084936207f  // 2*pi/32

// async 16B global->LDS (lds dest wave-uniform; HW adds lane*16)
__device__ __forceinline__ void async16(const void* g, void* l) {
    __builtin_amdgcn_global_load_lds(
        (const __attribute__((address_space(1))) unsigned int*)g,
        (__attribute__((address_space(3))) unsigned int*)l, 16, 0, 0);
}

// ---------------- gather patches into A_h [4096][768] f16 ----------------
__global__ __launch_bounds__(256) void gather_patch(const float* __restrict__ x,
        const float* __restrict__ grd, _Float16* __restrict__ A)
{
    int idx = blockIdx.x * 256 + threadIdx.x;
    int j   = idx % 768;
    int tok = idx / 768;
    int c = j >> 6, p = (j >> 3) & 7, q = j & 7;
    int wp = tok & 31, hp = (tok >> 5) & 31, b = tok >> 10;
    int hh = hp * 8 + p, ww = wp * 8 + q;
    float v;
    if (c < 10) v = x[((b * 256 + hh) * 256 + ww) * 10 + c];
    else        v = grd[((b * 256 + hh) * 256 + ww) * 2 + (c - 10)];
    A[idx] = (_Float16)v;
}

// ---------------- forward DFT along W (f16 in -> 17 complex f16), scale 1/32 ----------------
// prepass + fallback path. out layout [b,kw,h,c]
__global__ __launch_bounds__(256) void dft_fwd_w(const _Float16* __restrict__ th,
        _Float16* __restrict__ Xr, _Float16* __restrict__ Xi)
{
    __shared__ float2 lut[32];
    int bh = blockIdx.x;            // b*32 + h
    int tid = threadIdx.x;
    if (tid < 32) { float a = tid * STEP32; lut[tid] = make_float2(cosf(a), sinf(a)); }
    __syncthreads();
    int b = bh >> 5, h = bh & 31;
    int c = blockIdx.y * 256 + tid;
    float v[32];
    #pragma unroll
    for (int w = 0; w < 32; ++w) v[w] = (float)th[(bh * 32 + w) * 768 + c];
    for (int kw = 0; kw <= 16; ++kw) {
        float ar = 0.f, ai = 0.f;
        #pragma unroll
        for (int w = 0; w < 32; ++w) {
            float2 cs = lut[(kw * w) & 31];
            ar += v[w] * cs.x;
            ai -= v[w] * cs.y;
        }
        size_t g = ((size_t)(b * 17 + kw) * 32 + h) * 768 + c;
        Xr[g] = (_Float16)(ar * 0.03125f);
        Xi[g] = (_Float16)(ai * 0.03125f);
    }
}

// ---------------- inverse DFT along W (f16 in, [b,kw,h,c]) + f16 residual in-place ----------------
__global__ __launch_bounds__(256) void dft_inv_w(const _Float16* __restrict__ Yr,
        const _Float16* __restrict__ Yi, _Float16* __restrict__ th)
{
    __shared__ float2 lut[32];
    int bh = blockIdx.x;
    int tid = threadIdx.x;
    if (tid < 32) { float a = tid * STEP32; lut[tid] = make_float2(cosf(a), sinf(a)); }
    __syncthreads();
    int b = bh >> 5, h = bh & 31;
    int c = blockIdx.y * 256 + tid;
    float yr[17], yi[16];
    #pragma unroll
    for (int k = 0; k <= 16; ++k) yr[k] = (float)Yr[((size_t)(b * 17 + k) * 32 + h) * 768 + c];
    #pragma unroll
    for (int k = 1; k <= 15; ++k) yi[k] = (float)Yi[((size_t)(b * 17 + k) * 32 + h) * 768 + c];
    for (int w = 0; w < 32; ++w) {
        float val = yr[0] + ((w & 1) ? -yr[16] : yr[16]);
        #pragma unroll
        for (int k = 1; k <= 15; ++k) {
            float2 cs = lut[(k * w) & 31];
            val += 2.f * (yr[k] * cs.x - yi[k] * cs.y);
        }
        int gi = (bh * 32 + w) * 768 + c;
        th[gi] = (_Float16)(val * 0.03125f + (float)th[gi]);
    }
}

// ---------------- spectral weight prep: [i][o] fp32 -> [o][i] f16, 128 matrices ----------------
__global__ __launch_bounds__(256) void prep_specw(const float* __restrict__ w1,
        const float* __restrict__ w2, _Float16* __restrict__ out)
{
    __shared__ float tile[96][97];
    int mid = blockIdx.x;
    int n  = mid & 7;
    int ri = (mid >> 3) & 1;
    int l  = (mid >> 4) & 1;
    int d  = mid >> 5;
    const float* src = (l ? w2 : w1) + ((size_t)(d * 2 + ri) * 8 + n) * 9216;
    for (int idx = threadIdx.x; idx < 9216; idx += 256)
        tile[idx / 96][idx % 96] = src[idx];
    __syncthreads();
    _Float16* dst = out + (size_t)mid * 9216;
    for (int idx = threadIdx.x; idx < 9216; idx += 256)
        dst[idx] = (_Float16)tile[idx % 96][idx / 96];   // dst[o][i] = src[i][o]
}

// ---------------- fused spectral: H-DFT -> spec1(gelu) -> spec2(shrink) -> H-IDFT ----------------
// IN-PLACE on X ([b,kw,h,c] layout). grid (68 = b*17+kw, 8 = n); 256 thr = 4 waves.
__global__ __launch_bounds__(256) void spec_fused(
        _Float16* __restrict__ Xr, _Float16* __restrict__ Xi,
        const _Float16* __restrict__ W1r, const _Float16* __restrict__ W1i,
        const _Float16* __restrict__ W2r, const _Float16* __restrict__ W2i,
        const float* __restrict__ b1r, const float* __restrict__ b1i,
        const float* __restrict__ b2r, const float* __restrict__ b2i)
{
    __shared__ alignas(16) _Float16 Ec[1024], Es[1024];       // [m][k] twiddle 32x32
    __shared__ alignas(16) _Float16 XTr[3840], XTi[3840];     // [c][h] pad40; stage C: [o][kh]
    __shared__ alignas(16) _Float16 Zr[3328], Zi[3328];       // [kh][c] pad104; stage D out [h][c]
    __shared__ alignas(16) _Float16 Sr[3328], Si[3328];       // [kh][o] pad104

    const int bk = blockIdx.x;       // b*17 + kw
    const int n  = blockIdx.y;
    const int tid = threadIdx.x;
    const int wave = tid >> 6, lane = tid & 63;
    const int wr = wave >> 1, wc = wave & 1;
    const int lr = lane & 15, quad = lane >> 4;
    const size_t base = (size_t)bk * 24576 + n * 96;    // + h*768 + c

    for (int i = tid; i < 1024; i += 256) {
        int kh = i >> 5, h = i & 31;
        float a = ((kh * h) & 31) * STEP32;
        Ec[i] = (_Float16)cosf(a);
        Es[i] = (_Float16)sinf(a);
    }
    // vector load -> LDS transpose [c][h]
    for (int i = tid; i < 384; i += 256) {
        int h = i / 12, cc = (i % 12) * 8;
        half8 vr = *(const half8*)(Xr + base + (size_t)h * 768 + cc);
        half8 vi = *(const half8*)(Xi + base + (size_t)h * 768 + cc);
        #pragma unroll
        for (int e = 0; e < 8; ++e) {
            XTr[(cc + e) * 40 + h] = vr[e];
            XTi[(cc + e) * 40 + h] = vi[e];
        }
    }
    __syncthreads();

    const _Float16* w1r = W1r + (size_t)n * 9216;
    const _Float16* w1i = W1i + (size_t)n * 9216;
    const _Float16* w2r = W2r + (size_t)n * 9216;
    const _Float16* w2i = W2i + (size_t)n * 9216;

    half8 eC = *(const half8*)&Ec[(wr * 16 + lr) * 32 + quad * 8];
    half8 eS = *(const half8*)&Es[(wr * 16 + lr) * 32 + quad * 8];
    half8 eSn = -eS;

    // stage A: Z[kh][c] = DFT_h(X)
    {
        float4v zr[3], zi[3];
        #pragma unroll
        for (int j = 0; j < 3; ++j) { float4v z = {0,0,0,0}; zr[j] = z; zi[j] = z; }
        #pragma unroll
        for (int j = 0; j < 3; ++j) {
            int c = wc * 48 + j * 16 + lr;
            half8 xr = *(const half8*)&XTr[c * 40 + quad * 8];
            half8 xi = *(const half8*)&XTi[c * 40 + quad * 8];
            zr[j] = __builtin_amdgcn_mfma_f32_16x16x32_f16(eC,  xr, zr[j], 0, 0, 0);
            zr[j] = __builtin_amdgcn_mfma_f32_16x16x32_f16(eS,  xi, zr[j], 0, 0, 0);
            zi[j] = __builtin_amdgcn_mfma_f32_16x16x32_f16(eC,  xi, zi[j], 0, 0, 0);
            zi[j] = __builtin_amdgcn_mfma_f32_16x16x32_f16(eSn, xr, zi[j], 0, 0, 0);
        }
        #pragma unroll
        for (int j = 0; j < 3; ++j) {
            int c = wc * 48 + j * 16 + lr;
            #pragma unroll
            for (int r = 0; r < 4; ++r) {
                int kh = wr * 16 + quad * 4 + r;
                Zr[kh * 104 + c] = (_Float16)zr[j][r];
                Zi[kh * 104 + c] = (_Float16)zi[j][r];
            }
        }
    }
    __syncthreads();

    // stage B: S = gelu(Z @ W1 + b1)
    {
        float4v sr[3], si[3];
        #pragma unroll
        for (int j = 0; j < 3; ++j) { float4v z = {0,0,0,0}; sr[j] = z; si[j] = z; }
        #pragma unroll
        for (int kc = 0; kc < 3; ++kc) {
            half8 ar = *(const half8*)&Zr[(wr * 16 + lr) * 104 + kc * 32 + quad * 8];
            half8 ai = *(const half8*)&Zi[(wr * 16 + lr) * 104 + kc * 32 + quad * 8];
            half8 ain = -ai;
            #pragma unroll
            for (int j = 0; j < 3; ++j) {
                int o = wc * 48 + j * 16 + lr;
                half8 br = *(const half8*)&w1r[o * 96 + kc * 32 + quad * 8];
                half8 bi = *(const half8*)&w1i[o * 96 + kc * 32 + quad * 8];
                sr[j] = __builtin_amdgcn_mfma_f32_16x16x32_f16(ar,  br, sr[j], 0, 0, 0);
                sr[j] = __builtin_amdgcn_mfma_f32_16x16x32_f16(ain, bi, sr[j], 0, 0, 0);
                si[j] = __builtin_amdgcn_mfma_f32_16x16x32_f16(ai,  br, si[j], 0, 0, 0);
                si[j] = __builtin_amdgcn_mfma_f32_16x16x32_f16(ar,  bi, si[j], 0, 0, 0);
            }
        }
        #pragma unroll
        for (int j = 0; j < 3; ++j) {
            int o = wc * 48 + j * 16 + lr;
            float br = b1r[n * 96 + o], bi = b1i[n * 96 + o];
            #pragma unroll
            for (int r = 0; r < 4; ++r) {
                int kh = wr * 16 + quad * 4 + r;
                Sr[kh * 104 + o] = (_Float16)gelu_f(sr[j][r] + br);
                Si[kh * 104 + o] = (_Float16)gelu_f(si[j][r] + bi);
            }
        }
    }
    __syncthreads();

    // stage C: T = shrink(S @ W2 + b2) -> transposed T2T[o][kh] (alias XT)
    {
        float4v tr[3], ti[3];
        #pragma unroll
        for (int j = 0; j < 3; ++j) { float4v z = {0,0,0,0}; tr[j] = z; ti[j] = z; }
        #pragma unroll
        for (int kc = 0; kc < 3; ++kc) {
            half8 ar = *(const half8*)&Sr[(wr * 16 + lr) * 104 + kc * 32 + quad * 8];
            half8 ai = *(const half8*)&Si[(wr * 16 + lr) * 104 + kc * 32 + quad * 8];
            half8 ain = -ai;
            #pragma unroll
            for (int j = 0; j < 3; ++j) {
                int o = wc * 48 + j * 16 + lr;
                half8 br = *(const half8*)&w2r[o * 96 + kc * 32 + quad * 8];
                half8 bi = *(const half8*)&w2i[o * 96 + kc * 32 + quad * 8];
                tr[j] = __builtin_amdgcn_mfma_f32_16x16x32_f16(ar,  br, tr[j], 0, 0, 0);
                tr[j] = __builtin_amdgcn_mfma_f32_16x16x32_f16(ain, bi, tr[j], 0, 0, 0);
                ti[j] = __builtin_amdgcn_mfma_f32_16x16x32_f16(ai,  br, ti[j], 0, 0, 0);
                ti[j] = __builtin_amdgcn_mfma_f32_16x16x32_f16(ar,  bi, ti[j], 0, 0, 0);
            }
        }
        #pragma unroll
        for (int j = 0; j < 3; ++j) {
            int o = wc * 48 + j * 16 + lr;
            float br = b2r[n * 96 + o], bi = b2i[n * 96 + o];
            #pragma unroll
            for (int r = 0; r < 4; ++r) {
                int kh = wr * 16 + quad * 4 + r;
                XTr[o * 40 + kh] = (_Float16)shrink_f(tr[j][r] + br);
                XTi[o * 40 + kh] = (_Float16)shrink_f(ti[j][r] + bi);
            }
        }
    }
    __syncthreads();

    // stage D: Y[h][c] = IDFT_h(T2) -> Zr/Zi as [h][c] pad104
    {
        float4v yr[3], yi[3];
        #pragma unroll
        for (int j = 0; j < 3; ++j) { float4v z = {0,0,0,0}; yr[j] = z; yi[j] = z; }
        #pragma unroll
        for (int j = 0; j < 3; ++j) {
            int c = wc * 48 + j * 16 + lr;
            half8 t2r = *(const half8*)&XTr[c * 40 + quad * 8];
            half8 t2i = *(const half8*)&XTi[c * 40 + quad * 8];
            yr[j] = __builtin_amdgcn_mfma_f32_16x16x32_f16(eC,  t2r, yr[j], 0, 0, 0);
            yr[j] = __builtin_amdgcn_mfma_f32_16x16x32_f16(eSn, t2i, yr[j], 0, 0, 0);
            yi[j] = __builtin_amdgcn_mfma_f32_16x16x32_f16(eC,  t2i, yi[j], 0, 0, 0);
            yi[j] = __builtin_amdgcn_mfma_f32_16x16x32_f16(eS,  t2r, yi[j], 0, 0, 0);
        }
        #pragma unroll
        for (int j = 0; j < 3; ++j) {
            int c = wc * 48 + j * 16 + lr;
            #pragma unroll
            for (int r = 0; r < 4; ++r) {
                int h = wr * 16 + quad * 4 + r;
                Zr[h * 104 + c] = (_Float16)yr[j][r];
                Zi[h * 104 + c] = (_Float16)yi[j][r];
            }
        }
    }
    __syncthreads();

    // vector store back (in-place)
    for (int i = tid; i < 384; i += 256) {
        int h = i / 12, cc = (i % 12) * 8;
        half8 vr = *(const half8*)&Zr[h * 104 + cc];
        half8 vi = *(const half8*)&Zi[h * 104 + cc];
        *(half8*)(Xr + base + (size_t)h * 768 + cc) = vr;
        *(half8*)(Xi + base + (size_t)h * 768 + cc) = vi;
    }
}

// ---------------- f32 -> f16 elementwise (vectorized x4) ----------------
__global__ __launch_bounds__(256) void cvt_f16(const float* __restrict__ in,
        _Float16* __restrict__ out)
{
    int i = blockIdx.x * 256 + threadIdx.x;
    float4 v = ((const float4*)in)[i];
    half4v o;
    o.x = (_Float16)v.x; o.y = (_Float16)v.y; o.z = (_Float16)v.z; o.w = (_Float16)v.w;
    ((half4v*)out)[i] = o;
}

// ---------------- f32 [K][N] -> f16 [N][K] transpose ----------------
__global__ __launch_bounds__(256) void cvt_transpose(const float* __restrict__ in,
        _Float16* __restrict__ out, int K, int N)
{
    __shared__ float tile[32][33];
    int kb = blockIdx.x * 32, nb = blockIdx.y * 32;
    int tx = threadIdx.x & 31, ty = threadIdx.x >> 5;
    #pragma unroll
    for (int r = 0; r < 32; r += 8)
        tile[ty + r][tx] = in[(size_t)(kb + ty + r) * N + nb + tx];
    __syncthreads();
    #pragma unroll
    for (int r = 0; r < 32; r += 8)
        out[(size_t)(nb + ty + r) * K + kb + tx] = (_Float16)tile[tx][ty + r];
}

// ---------------- fp16 MFMA GEMM, double-buffered LDS, 2D-XCD swizzle ----------------
// OUT_MODE: 1 = f16, 3 = f32 pixel-shuffle scatter,
//           4 = f16 + fused forward W-DFT epilogue (fc2: writes XR/XI [b,kw,h,c])
template<int BN, int OUT_MODE, int ACT>
__global__ __launch_bounds__(256) void gemm_h(const _Float16* __restrict__ A,
        const _Float16* __restrict__ Bt, const float* __restrict__ bias,
        const float* __restrict__ pos, float* __restrict__ C32,
        _Float16* __restrict__ C16, _Float16* __restrict__ XR,
        _Float16* __restrict__ XI, int M, int N, int K, int f_idx)
{
    constexpr int WN  = BN / 2;
    constexpr int FN  = WN / 16;
    constexpr int NBJ = BN / 64;
    __shared__ _Float16 Al[2][128 * 32];
    __shared__ _Float16 Bl[2][BN * 32];

    const int tid  = threadIdx.x;
    const int wave = tid >> 6;
    const int lane = tid & 63;
    const int wr   = wave >> 1;
    const int wc   = wave & 1;
    const int lr   = lane & 15;
    const int quad = lane >> 4;

    // XCD swizzle: prefer 2D (4 row-groups x 2 col-groups -> per-XCD A+B fits 4MB L2)
    const int gx = gridDim.x, gy = gridDim.y, nbk = gx * gy;
    int bx = blockIdx.x, by = blockIdx.y;
    if (!(gy & 3) && !(gx & 1)) {
        int id = by * gx + bx;
        int xcd = id & 7, j = id >> 3;
        int cols = gx >> 1;
        int rows = gy >> 2;
        int jr = j / cols, jc = j % cols;
        by = (xcd >> 1) * rows + jr;
        bx = (xcd & 1) * cols + jc;
    } else if (!(nbk & 7)) {
        int id  = by * gx + bx;
        int id2 = (id & 7) * (nbk >> 3) + (id >> 3);
        by = id2 / gx; bx = id2 % gx;
    }
    const int row0 = by * 128;
    const int col0 = bx * BN;

    const int srow = lane >> 2;
    const int skof = (lane & 3) * 8;

    auto stage = [&](int b, int k0) {
        #pragma unroll
        for (int j = 0; j < 2; ++j)
            async16(A + (size_t)(row0 + j * 64 + wave * 16 + srow) * K + k0 + skof,
                    &Al[b][(j * 64 + wave * 16) * 32]);
        #pragma unroll
        for (int j = 0; j < NBJ; ++j)
            async16(Bt + (size_t)(col0 + j * 64 + wave * 16 + srow) * K + k0 + skof,
                    &Bl[b][(j * 64 + wave * 16) * 32]);
    };

    float4v acc[4][FN];
    #pragma unroll
    for (int i = 0; i < 4; ++i)
        #pragma unroll
        for (int j = 0; j < FN; ++j) {
            float4v z = {0.f, 0.f, 0.f, 0.f};
            acc[i][j] = z;
        }

    const int KT = K >> 5;
    stage(0, 0);
    for (int kt = 0; kt < KT; ++kt) {
        __syncthreads();
        if (kt + 1 < KT) stage((kt + 1) & 1, (kt + 1) << 5);
        const int cb = kt & 1;
        half8 af[4], bf[FN];
        #pragma unroll
        for (int i = 0; i < 4; ++i)
            af[i] = *(const half8*)&Al[cb][(wr * 64 + i * 16 + lr) * 32 + quad * 8];
        #pragma unroll
        for (int j = 0; j < FN; ++j)
            bf[j] = *(const half8*)&Bl[cb][(wc * WN + j * 16 + lr) * 32 + quad * 8];
        #pragma unroll
        for (int i = 0; i < 4; ++i)
            #pragma unroll
            for (int j = 0; j < FN; ++j)
                acc[i][j] = __builtin_amdgcn_mfma_f32_16x16x32_f16(af[i], bf[j], acc[i][j], 0, 0, 0);
    }

    if constexpr (OUT_MODE == 4) {
        // fc2 epilogue: f16 write + stage tile + fused forward W-DFT
        __shared__ alignas(16) _Float16 Tl[4 * 64 * 32];   // [h][c][w]
        __shared__ alignas(16) _Float16 ECl[1024], ESl[1024];
        for (int i = tid; i < 1024; i += 256) {
            int kw = i >> 5, w = i & 31;
            float a = ((kw * w) & 31) * STEP32;
            ECl[i] = (_Float16)(cosf(a) * 0.03125f);
            ESl[i] = (_Float16)(-sinf(a) * 0.03125f);
        }
        #pragma unroll
        for (int j = 0; j < FN; ++j) {
            int col = col0 + wc * WN + j * 16 + lr;
            float bj = bias[col];
            #pragma unroll
            for (int i = 0; i < 4; ++i) {
                int row = row0 + wr * 64 + i * 16 + quad * 4;
                #pragma unroll
                for (int r = 0; r < 4; ++r) {
                    float v = acc[i][j][r] + bj;
                    size_t gi = (size_t)(row + r) * N + col;
                    C16[gi] = (_Float16)v;
                    int lrow = row + r - row0;
                    Tl[(((lrow >> 5) * 64) + (col - col0)) * 32 + (lrow & 31)] = (_Float16)v;
                }
            }
        }
        __syncthreads();
        // per-wave h-row DFT: X[kw][c] = E @ T   (wave = local h)
        const int b  = row0 >> 10;
        const int hp = ((row0 >> 5) & 31) + wave;
        half8 eC0 = *(const half8*)&ECl[lr * 32 + quad * 8];
        half8 eC1 = *(const half8*)&ECl[(16 + lr) * 32 + quad * 8];
        half8 eS0 = *(const half8*)&ESl[lr * 32 + quad * 8];
        half8 eS1 = *(const half8*)&ESl[(16 + lr) * 32 + quad * 8];
        float4v xr[2][4], xi[2][4];
        #pragma unroll
        for (int m = 0; m < 2; ++m)
            #pragma unroll
            for (int nj = 0; nj < 4; ++nj) {
                float4v z = {0.f, 0.f, 0.f, 0.f};
                xr[m][nj] = z; xi[m][nj] = z;
            }
        #pragma unroll
        for (int nj = 0; nj < 4; ++nj) {
            half8 tb = *(const half8*)&Tl[((wave * 64) + nj * 16 + lr) * 32 + quad * 8];
            xr[0][nj] = __builtin_amdgcn_mfma_f32_16x16x32_f16(eC0, tb, xr[0][nj], 0, 0, 0);
            xr[1][nj] = __builtin_amdgcn_mfma_f32_16x16x32_f16(eC1, tb, xr[1][nj], 0, 0, 0);
            xi[0][nj] = __builtin_amdgcn_mfma_f32_16x16x32_f16(eS0, tb, xi[0][nj], 0, 0, 0);
            xi[1][nj] = __builtin_amdgcn_mfma_f32_16x16x32_f16(eS1, tb, xi[1][nj], 0, 0, 0);
        }
        #pragma unroll
        for (int m = 0; m < 2; ++m)
            #pragma unroll
            for (int r = 0; r < 4; ++r) {
                int kw = m * 16 + quad * 4 + r;
                if (kw < 17) {
                    #pragma unroll
                    for (int nj = 0; nj < 4; ++nj) {
                        int c = col0 + nj * 16 + lr;
                        size_t g = ((size_t)(b * 17 + kw) * 32 + hp) * 768 + c;
                        XR[g] = (_Float16)xr[m][nj][r];
                        XI[g] = (_Float16)xi[m][nj][r];
                    }
                }
            }
    } else {
        #pragma unroll
        for (int j = 0; j < FN; ++j) {
            int col = col0 + wc * WN + j * 16 + lr;
            float bj = bias[col];
            #pragma unroll
            for (int i = 0; i < 4; ++i) {
                int row = row0 + wr * 64 + i * 16 + quad * 4;
                #pragma unroll
                for (int r = 0; r < 4; ++r) {
                    float v = acc[i][j][r] + bj;
                    if (pos) v += pos[(size_t)((row + r) & 1023) * N + col];
                    if (ACT) v = gelu_f(v);
                    if (OUT_MODE == 3) {
                        int rowv = row + r;
                        int bq = rowv >> 10, hp = (rowv >> 5) & 31, wp = rowv & 31;
                        int p = col >> 3, q = col & 7;
                        C32[(((size_t)(bq * 256 + hp * 8 + p)) * 256 + wp * 8 + q) * 4 + f_idx] = v;
                    } else {
                        C16[(size_t)(row + r) * N + col] = (_Float16)v;
                    }
                }
            }
        }
    }
}

// ---------------- launch ----------------
extern "C" void kernel_launch(void* const* d_in, const int* in_sizes, int n_in,
                              void* d_out, int out_size, void* d_ws, size_t ws_size,
                              hipStream_t stream) {
    const float* x        = (const float*)d_in[0];
    const float* grd      = (const float*)d_in[1];
    const float* conv_w   = (const float*)d_in[2];
    const float* conv_b   = (const float*)d_in[3];
    const float* pos_emb  = (const float*)d_in[4];
    const float* w1       = (const float*)d_in[5];
    const float* b1       = (const float*)d_in[6];
    const float* w2       = (const float*)d_in[7];
    const float* b2       = (const float*)d_in[8];
    const float* fc1_w    = (const float*)d_in[9];
    const float* fc1_b    = (const float*)d_in[10];
    const float* fc2_w    = (const float*)d_in[11];
    const float* fc2_b    = (const float*)d_in[12];
    const float* head_w1  = (const float*)d_in[13];
    const float* head_b1  = (const float*)d_in[14];
    const float* head_w2  = (const float*)d_in[15];
    const float* head_b2  = (const float*)d_in[16];
    float* out = (float*)d_out;
    float* ws  = (float*)d_ws;

    // ---- workspace layout, sizes in float units ----
    float* pf = ws;
    _Float16* t_h     = (_Float16*)pf; pf += 1572864;   // 4096x768 f16 (residual state)
    _Float16* Wsp     = (_Float16*)pf; pf += 589824;    // 128x9216 f16 spectral weights
    _Float16* h1t     = (_Float16*)pf; pf += 589824;    // [1536][768] f16
    _Float16* h2t     = (_Float16*)pf; pf += 49152;     // [64][1536] f16
    _Float16* convw_h = (_Float16*)pf; pf += 294912;    // 768x768 f16 (prepass only)
    float* alias    = pf;              pf += 6291456;   // hid_h 4096x3072 f16
    _Float16* hid_h = (_Float16*)alias;
    _Float16* WtAll = (_Float16*)pf;   pf += 9437184;   // 8 x [N][K] fc weights f16
    // fallback xa inside alias (hid dead when xa live); full mode: dedicated xa after WtAll
    _Float16* xa_r_fb = (_Float16*)alias;
    _Float16* xa_i_fb = (_Float16*)(alias + 835584);
    _Float16* xa_r_fu = (_Float16*)pf;                  // +835,584 f
    _Float16* xa_i_fu = (_Float16*)(pf + 835584);       // +835,584 f
    size_t full_total = (size_t)(pf - ws) + 1671168;    // 20,496,384 f = 82.0 MB
    bool full = ws_size >= full_total * 4ull;
    _Float16* xa_r = full ? xa_r_fu : xa_r_fb;
    _Float16* xa_i = full ? xa_i_fu : xa_i_fb;
    _Float16* A_h  = (_Float16*)alias;                  // prepass-only (gather input, dead after)

    // ---- prepass ----
    prep_specw<<<dim3(128), 256, 0, stream>>>(w1, w2, Wsp);
    cvt_f16<<<dim3(576), 256, 0, stream>>>(conv_w, convw_h);
    cvt_transpose<<<dim3(24, 48), 256, 0, stream>>>(head_w1, h1t, 768, 1536);
    cvt_transpose<<<dim3(48, 2), 256, 0, stream>>>(head_w2, h2t, 1536, 64);
    for (int d = 0; d < 4; ++d) {
        cvt_transpose<<<dim3(24, 96), 256, 0, stream>>>(
            fc1_w + (size_t)d * 2359296, WtAll + (size_t)(2 * d) * 2359296, 768, 3072);
        cvt_transpose<<<dim3(96, 24), 256, 0, stream>>>(
            fc2_w + (size_t)d * 2359296, WtAll + (size_t)(2 * d + 1) * 2359296, 3072, 768);
    }
    gather_patch<<<dim3(12288), 256, 0, stream>>>(x, grd, A_h);
    gemm_h<128, 1, 0><<<dim3(6, 32), 256, 0, stream>>>(
        A_h, convw_h, conv_b, pos_emb, nullptr, t_h, nullptr, nullptr, 4096, 768, 768, 0);
    dft_fwd_w<<<dim3(128, 3), 256, 0, stream>>>(t_h, xa_r, xa_i);

    for (int f = 0; f < 4; ++f) {
        for (int d = 0; d < 4; ++d) {
            // fused H-DFT + complex MLP + H-IDFT (in-place on xa)
            spec_fused<<<dim3(68, 8), 256, 0, stream>>>(
                xa_r, xa_i,
                Wsp + (size_t)(d * 4 + 0) * 73728, Wsp + (size_t)(d * 4 + 1) * 73728,
                Wsp + (size_t)(d * 4 + 2) * 73728, Wsp + (size_t)(d * 4 + 3) * 73728,
                b1 + d * 1536, b1 + d * 1536 + 768,
                b2 + d * 1536, b2 + d * 1536 + 768);
            // irfft2 W-pass + f16 residual (in place on t_h)
            dft_inv_w<<<dim3(128, 3), 256, 0, stream>>>(xa_r, xa_i, t_h);
            // channel MLP
            gemm_h<128, 1, 1><<<dim3(24, 32), 256, 0, stream>>>(
                t_h, WtAll + (size_t)(2 * d) * 2359296, fc1_b + d * 3072,
                nullptr, nullptr, hid_h, nullptr, nullptr, 4096, 3072, 768, 0);
            if (full) {
                // fc2 + fused forward W-DFT (seeds xa for the next spectral block)
                gemm_h<64, 4, 0><<<dim3(12, 32), 256, 0, stream>>>(
                    hid_h, WtAll + (size_t)(2 * d + 1) * 2359296, fc2_b + d * 768,
                    nullptr, nullptr, t_h, xa_r, xa_i, 4096, 768, 3072, 0);
            } else {
                gemm_h<64, 1, 0><<<dim3(12, 32), 256, 0, stream>>>(
                    hid_h, WtAll + (size_t)(2 * d + 1) * 2359296, fc2_b + d * 768,
                    nullptr, nullptr, t_h, nullptr, nullptr, 4096, 768, 3072, 0);
                dft_fwd_w<<<dim3(128, 3), 256, 0, stream>>>(t_h, xa_r, xa_i);
            }
        }
        // head on current state (t_h from fc2)
        gemm_h<128, 1, 1><<<dim3(12, 32), 256, 0, stream>>>(
            t_h, h1t, head_b1, nullptr, nullptr, hid_h, nullptr, nullptr, 4096, 1536, 768, 0);
        gemm_h<64, 3, 0><<<dim3(1, 32), 256, 0, stream>>>(
            hid_h, h2t, head_b2, nullptr, out, nullptr, nullptr, nullptr, 4096, 64, 1536, f);
    }
}